// Round 4
// baseline (188.071 us; speedup 1.0000x reference)
//
#include <hip/hip_runtime.h>
#include <math.h>

// Net_Without_GINEgPool: GATConv(32,128,h=4) + TopKPooling(0.8) + max/mean pool + MLP head.
// R4: 2-nodes-per-wave GAT (__expf, width-32 reductions, 16-col lanes), fused stage1
//     (compute_h + build_slots + misc, XCD-aligned roles), 16-way pool partials.

#define N_NODES 32000
#define B_GRAPHS 32
#define NPG 1000
#define DEGC 10
#define E_EDGES (N_NODES*DEGC)
#define HD 512
#define F_IN 32
#define KKEEP 800
#define SLOPE 0.2f
#define CAP 32

#define NPB 32
#define CH_BLOCKS 1000   // compute_h role
#define BS_BLOCKS 640    // build_slots role

// ---------------- stage1: fused compute_h | build_slots | misc ----------------
__global__ __launch_bounds__(256) void stage1_kernel(
    const float* __restrict__ x, const float* __restrict__ W,
    const float* __restrict__ att_src, const float* __restrict__ att_dst,
    const float* __restrict__ topk_w, const int* __restrict__ dst,
    float* __restrict__ h, float* __restrict__ a_s, float* __restrict__ a_d,
    int* __restrict__ counts, int* __restrict__ slots, float* __restrict__ misc)
{
    int b = blockIdx.x;
    int tid = threadIdx.x;
    if (b < CH_BLOCKS) {
        // ---- compute_h: nodes XCD-aligned with gat_agg consumer ----
        __shared__ float s_x[NPB*F_IN];    // 4 KB
        __shared__ float s_Wsd[256];       // [0,128)=Ws, [128,256)=Wd, entry f*4+hh
        int n0 = (b & 7)*4000 + (b >> 3)*NPB;
        {   // per-block fold of W with att vectors (W is L2-hot)
            int f = (tid & 127) >> 2, hh = tid & 3;
            const float* av = (tid < 128) ? att_src : att_dst;
            const float* wp = W + f*HD + hh*128;
            const float* ap = av + hh*128;
            float s = 0.f;
            #pragma unroll 8
            for (int d = 0; d < 128; ++d) s = fmaf(wp[d], ap[d], s);
            s_Wsd[tid] = s;
        }
        float wc0[F_IN], wc1[F_IN];
        #pragma unroll
        for (int f = 0; f < F_IN; ++f) {
            wc0[f] = W[f*HD + tid];
            wc1[f] = W[f*HD + tid + 256];
        }
        const float4* xg = (const float4*)(x + (size_t)n0*F_IN);
        float4* sx4 = (float4*)s_x;
        if (tid < NPB*F_IN/4) sx4[tid] = xg[tid];
        __syncthreads();
        for (int n = 0; n < NPB; ++n) {
            const float4* xr = (const float4*)(s_x + n*F_IN);
            float acc0 = 0.f, acc1 = 0.f;
            #pragma unroll
            for (int f4 = 0; f4 < F_IN/4; ++f4) {
                float4 xv = xr[f4];
                acc0 = fmaf(xv.x, wc0[f4*4+0], acc0); acc1 = fmaf(xv.x, wc1[f4*4+0], acc1);
                acc0 = fmaf(xv.y, wc0[f4*4+1], acc0); acc1 = fmaf(xv.y, wc1[f4*4+1], acc1);
                acc0 = fmaf(xv.z, wc0[f4*4+2], acc0); acc1 = fmaf(xv.z, wc1[f4*4+2], acc1);
                acc0 = fmaf(xv.w, wc0[f4*4+3], acc0); acc1 = fmaf(xv.w, wc1[f4*4+3], acc1);
            }
            h[(size_t)(n0+n)*HD + tid]       = acc0;
            h[(size_t)(n0+n)*HD + tid + 256] = acc1;
        }
        {   // a_s/a_d: tid = n*8 + hh*2 + which
            int n = tid >> 3, hh = (tid >> 1) & 3, which = tid & 1;
            const float* Wx = s_Wsd + which*128;
            const float* xr = s_x + n*F_IN;
            float s = 0.f;
            #pragma unroll
            for (int f = 0; f < F_IN; ++f) s = fmaf(xr[f], Wx[f*4+hh], s);
            float* dp = which ? a_d : a_s;
            dp[(size_t)(n0+n)*4 + hh] = s;
        }
    } else if (b < CH_BLOCKS + BS_BLOCKS) {
        // ---- build_slots: XCD-local edge ranges (graph-contiguous edge array) ----
        int q = b - CH_BLOCKS;               // (CH_BLOCKS%8==0 keeps q%8 == dispatch XCD)
        int e0 = (q & 7)*40000 + (q >> 3)*500;
        for (int i = tid; i < 500; i += 256) {
            int e = e0 + i;
            int d = dst[e];
            int p = atomicAdd(&counts[d], 1);
            if (p < CAP) slots[d*CAP + p] = e;
        }
    } else {
        // ---- misc: 1/||topk_w|| ----
        __shared__ float red[256];
        float tw0 = topk_w[tid], tw1 = topk_w[tid+256];
        red[tid] = tw0*tw0 + tw1*tw1;
        __syncthreads();
        for (int s = 128; s > 0; s >>= 1) { if (tid < s) red[tid] += red[tid+s]; __syncthreads(); }
        if (tid == 0) misc[0] = 1.0f / sqrtf(red[0]);
    }
}

// ---------------- GAT: 2 nodes per wave, 32-lane halves ----------------
__global__ __launch_bounds__(256) void gat_agg_kernel(
    const float* __restrict__ h, const float* __restrict__ a_s, const float* __restrict__ a_d,
    const int* __restrict__ counts, const int* __restrict__ slots, const int* __restrict__ esrc,
    const float* __restrict__ bias, const float* __restrict__ topk_w, const float* __restrict__ misc,
    float* __restrict__ x1, float* __restrict__ scores)
{
    __shared__ int    s_src[8][32];
    __shared__ float4 s_al[8][32];
    int tid  = threadIdx.x;
    int wid  = tid >> 6, lane = tid & 63;
    int hl   = lane & 31;                    // lane within half (edge slot)
    int nn   = wid*2 + (lane >> 5);          // node slot within block [0,8)
    int grp  = (blockIdx.x & 7)*500 + (blockIdx.x >> 3);  // XCD k -> nodes [k*4000,+4000)
    int node = grp*8 + nn;
    int deg  = min(counts[node], CAP);

    // canonical edge order: rank-sort eids within the 32-lane half
    int key = (hl < deg) ? slots[node*CAP + hl] : (0x7FFF0000 + lane);
    int dm  = max(deg, __shfl_xor(deg, 32, 64));
    int rank = 0;
    for (int j = 0; j < dm; ++j)
        rank += (__shfl(key, (lane & 32) + j, 64) < key) ? 1 : 0;
    if (hl >= deg) rank = hl;
    int sorted_eid = __builtin_amdgcn_ds_permute(((lane & 32) + rank) << 2, key);

    int src = node;
    if (hl < deg) src = esrc[sorted_eid];

    float4 ad    = *(const float4*)(a_d + (size_t)node*4);
    float4 aself = *(const float4*)(a_s + (size_t)node*4);
    float4 asrc  = make_float4(0.f,0.f,0.f,0.f);
    if (hl < deg) asrc = *(const float4*)(a_s + (size_t)src*4);

    float t[4], ts[4];
    {
        float u;
        u = asrc.x + ad.x;  t[0]  = u > 0.f ? u : SLOPE*u;
        u = asrc.y + ad.y;  t[1]  = u > 0.f ? u : SLOPE*u;
        u = asrc.z + ad.z;  t[2]  = u > 0.f ? u : SLOPE*u;
        u = asrc.w + ad.w;  t[3]  = u > 0.f ? u : SLOPE*u;
        u = aself.x + ad.x; ts[0] = u > 0.f ? u : SLOPE*u;
        u = aself.y + ad.y; ts[1] = u > 0.f ? u : SLOPE*u;
        u = aself.z + ad.z; ts[2] = u > 0.f ? u : SLOPE*u;
        u = aself.w + ad.w; ts[3] = u > 0.f ? u : SLOPE*u;
    }
    #pragma unroll
    for (int hh = 0; hh < 4; ++hh) if (hl >= deg) t[hh] = -INFINITY;

    float al[4], alself[4];
    #pragma unroll
    for (int hh = 0; hh < 4; ++hh) {
        float m = t[hh];
        #pragma unroll
        for (int msk = 1; msk < 32; msk <<= 1) m = fmaxf(m, __shfl_xor(m, msk, 64));
        m = fmaxf(m, ts[hh]);
        float ex  = (hl < deg) ? __expf(t[hh] - m) : 0.f;
        float exs = __expf(ts[hh] - m);
        float den = ex;
        #pragma unroll
        for (int msk = 1; msk < 32; msk <<= 1) den += __shfl_xor(den, msk, 64);
        den += exs;
        float inv = 1.0f / den;
        al[hh]     = ex * inv;
        alself[hh] = exs * inv;
    }
    if (hl < deg) {
        s_src[nn][hl] = src;
        s_al[nn][hl]  = make_float4(al[0], al[1], al[2], al[3]);
    }
    __syncthreads();

    // aggregation: lane owns cols [hl*16, +16) of its node; head = hl>>3
    int col0 = hl*16;
    int head = hl >> 3;
    const float* alsp = (const float*)&s_al[nn][0];   // [32][4] floats
    float4 accA = make_float4(0,0,0,0), accB = make_float4(0,0,0,0);
    float4 accC = make_float4(0,0,0,0), accD = make_float4(0,0,0,0);
    #define EDGE_STEP(E_IDX) { \
        int se = s_src[nn][E_IDX]; \
        float av = alsp[(E_IDX)*4 + head]; \
        const float4* hp = (const float4*)(h + (size_t)se*HD + col0); \
        float4 v0 = hp[0], v1 = hp[1], v2 = hp[2], v3 = hp[3]; \
        accA.x = fmaf(av, v0.x, accA.x); accA.y = fmaf(av, v0.y, accA.y); \
        accA.z = fmaf(av, v0.z, accA.z); accA.w = fmaf(av, v0.w, accA.w); \
        accB.x = fmaf(av, v1.x, accB.x); accB.y = fmaf(av, v1.y, accB.y); \
        accB.z = fmaf(av, v1.z, accB.z); accB.w = fmaf(av, v1.w, accB.w); \
        accC.x = fmaf(av, v2.x, accC.x); accC.y = fmaf(av, v2.y, accC.y); \
        accC.z = fmaf(av, v2.z, accC.z); accC.w = fmaf(av, v2.w, accC.w); \
        accD.x = fmaf(av, v3.x, accD.x); accD.y = fmaf(av, v3.y, accD.y); \
        accD.z = fmaf(av, v3.z, accD.z); accD.w = fmaf(av, v3.w, accD.w); }
    int e = 0;
    for (; e + 2 <= deg; e += 2) { EDGE_STEP(e); EDGE_STEP(e+1); }
    if (e < deg) EDGE_STEP(e);
    #undef EDGE_STEP
    {   // self-loop last (reference concat order)
        float s01 = (head & 1) ? alself[1] : alself[0];
        float s23 = (head & 1) ? alself[3] : alself[2];
        float av  = (head & 2) ? s23 : s01;
        const float4* hp = (const float4*)(h + (size_t)node*HD + col0);
        float4 v0 = hp[0], v1 = hp[1], v2 = hp[2], v3 = hp[3];
        accA.x = fmaf(av, v0.x, accA.x); accA.y = fmaf(av, v0.y, accA.y);
        accA.z = fmaf(av, v0.z, accA.z); accA.w = fmaf(av, v0.w, accA.w);
        accB.x = fmaf(av, v1.x, accB.x); accB.y = fmaf(av, v1.y, accB.y);
        accB.z = fmaf(av, v1.z, accB.z); accB.w = fmaf(av, v1.w, accB.w);
        accC.x = fmaf(av, v2.x, accC.x); accC.y = fmaf(av, v2.y, accC.y);
        accC.z = fmaf(av, v2.z, accC.z); accC.w = fmaf(av, v2.w, accC.w);
        accD.x = fmaf(av, v3.x, accD.x); accD.y = fmaf(av, v3.y, accD.y);
        accD.z = fmaf(av, v3.z, accD.z); accD.w = fmaf(av, v3.w, accD.w);
    }
    const float4* bp  = (const float4*)(bias + col0);
    const float4* twp = (const float4*)(topk_w + col0);
    float4 b0 = bp[0], b1 = bp[1], b2 = bp[2], b3 = bp[3];
    float4 r0, r1, r2, r3;
    r0.x = fmaxf(accA.x + b0.x, 0.f); r0.y = fmaxf(accA.y + b0.y, 0.f);
    r0.z = fmaxf(accA.z + b0.z, 0.f); r0.w = fmaxf(accA.w + b0.w, 0.f);
    r1.x = fmaxf(accB.x + b1.x, 0.f); r1.y = fmaxf(accB.y + b1.y, 0.f);
    r1.z = fmaxf(accB.z + b1.z, 0.f); r1.w = fmaxf(accB.w + b1.w, 0.f);
    r2.x = fmaxf(accC.x + b2.x, 0.f); r2.y = fmaxf(accC.y + b2.y, 0.f);
    r2.z = fmaxf(accC.z + b2.z, 0.f); r2.w = fmaxf(accC.w + b2.w, 0.f);
    r3.x = fmaxf(accD.x + b3.x, 0.f); r3.y = fmaxf(accD.y + b3.y, 0.f);
    r3.z = fmaxf(accD.z + b3.z, 0.f); r3.w = fmaxf(accD.w + b3.w, 0.f);
    float4* xp = (float4*)(x1 + (size_t)node*HD + col0);
    xp[0] = r0; xp[1] = r1; xp[2] = r2; xp[3] = r3;

    float4 w0 = twp[0], w1 = twp[1], w2 = twp[2], w3 = twp[3];
    float p = r0.x*w0.x + r0.y*w0.y + r0.z*w0.z + r0.w*w0.w
            + r1.x*w1.x + r1.y*w1.y + r1.z*w1.z + r1.w*w1.w
            + r2.x*w2.x + r2.y*w2.y + r2.z*w2.z + r2.w*w2.w
            + r3.x*w3.x + r3.y*w3.y + r3.z*w3.z + r3.w*w3.w;
    #pragma unroll
    for (int msk = 1; msk < 32; msk <<= 1) p += __shfl_xor(p, msk, 64);
    if (hl == 0) {
        float dotv = p * misc[0];
        float eu   = __expf(2.f * fabsf(dotv));       // tanh via exp, saturation-safe
        float th   = 1.f - 2.f/(eu + 1.f);
        scores[node] = copysignf(th, dotv);
    }
}

// ---------------- TopK per graph via exact rank; 4 blocks/graph ----------------
__global__ __launch_bounds__(256) void topk_kernel(const float* __restrict__ scores,
                                                   int* __restrict__ kept_ids,
                                                   float* __restrict__ kept_vals)
{
    int g = blockIdx.x, part = blockIdx.y;
    __shared__ float s[NPG];
    int tid = threadIdx.x;
    for (int i = tid; i < NPG; i += 256) s[i] = scores[g*NPG + i];
    __syncthreads();
    int i = part*250 + tid;
    if (tid < 250) {
        float si = s[i];
        int rank = 0;
        for (int j = 0; j < NPG; ++j) {
            float sj = s[j];
            rank += (sj > si) || (sj == si && j < i);
        }
        if (rank < KKEEP) {
            kept_ids[g*KKEEP + rank]  = g*NPG + i;
            kept_vals[g*KKEEP + rank] = si;
        }
    }
}

// ---------------- pool partials: 16 chunks x 50 rows, XCD-aligned ----------------
#define RCHUNK 50
#define NCHUNK 16
__global__ __launch_bounds__(128) void pool_partial_kernel(
    const float* __restrict__ x1, const int* __restrict__ kept_ids,
    const float* __restrict__ kept_vals, float* __restrict__ pmax, float* __restrict__ psum)
{
    int bid = blockIdx.x;                 // 512
    int k = bid & 7, q = bid >> 3;        // XCD k serves graphs 4k..4k+3
    int g = k*4 + (q & 3), c = q >> 2;    // c in [0,16)
    int tid = threadIdx.x;                // 128, float4 col = tid*4
    __shared__ int   ids[RCHUNK];
    __shared__ float vals[RCHUNK];
    if (tid < RCHUNK) {
        ids[tid]  = kept_ids[g*KKEEP + c*RCHUNK + tid];
        vals[tid] = kept_vals[g*KKEEP + c*RCHUNK + tid];
    }
    __syncthreads();
    float4 mx = make_float4(-INFINITY,-INFINITY,-INFINITY,-INFINITY);
    float4 sm = make_float4(0.f,0.f,0.f,0.f);
    for (int r = 0; r < RCHUNK; ++r) {
        float4 v = *(const float4*)(x1 + (size_t)ids[r]*HD + tid*4);
        float vl = vals[r];
        v.x *= vl; v.y *= vl; v.z *= vl; v.w *= vl;
        mx.x = fmaxf(mx.x, v.x); mx.y = fmaxf(mx.y, v.y);
        mx.z = fmaxf(mx.z, v.z); mx.w = fmaxf(mx.w, v.w);
        sm.x += v.x; sm.y += v.y; sm.z += v.z; sm.w += v.w;
    }
    *(float4*)(pmax + (size_t)(g*NCHUNK + c)*HD + tid*4) = mx;
    *(float4*)(psum + (size_t)(g*NCHUNK + c)*HD + tid*4) = sm;
}

// ---------------- finalize pool + MLP head (k-split, 256 threads) ----------------
__global__ __launch_bounds__(256) void mlp_kernel(
    const float* __restrict__ pmax, const float* __restrict__ psum,
    const float* __restrict__ w1, const float* __restrict__ b1,
    const float* __restrict__ w2, const float* __restrict__ b2,
    const float* __restrict__ w3, const float* __restrict__ b3,
    float* __restrict__ out)
{
    int g = blockIdx.x;
    int tid = threadIdx.x; // 256
    __shared__ float sx[1024];
    __shared__ float part1[8][128];
    __shared__ float sh1[128];
    __shared__ float part2[4][64];
    __shared__ float sh2[64];
    __shared__ float part3[8][8];
    __shared__ float slog[8];

    {   // pool finalize over 16 partials
        int half = tid >> 7;           // 0 = max, 1 = mean
        int c4 = tid & 127;
        const float* basep = half ? psum : pmax;
        float4 r = *(const float4*)(basep + (size_t)(g*NCHUNK)*HD + c4*4);
        #pragma unroll
        for (int c = 1; c < NCHUNK; ++c) {
            float4 v = *(const float4*)(basep + (size_t)(g*NCHUNK + c)*HD + c4*4);
            if (half) { r.x += v.x; r.y += v.y; r.z += v.z; r.w += v.w; }
            else {
                r.x = fmaxf(r.x, v.x); r.y = fmaxf(r.y, v.y);
                r.z = fmaxf(r.z, v.z); r.w = fmaxf(r.w, v.w);
            }
        }
        if (half) { const float inv = 1.0f/KKEEP; r.x *= inv; r.y *= inv; r.z *= inv; r.w *= inv; }
        *(float4*)(sx + half*512 + c4*4) = r;
    }
    __syncthreads();

    {   // layer 1: 1024 -> 128, 8 k-slices of 128
        int ks = tid >> 5, tc = tid & 31;
        const float* w1p = w1 + (size_t)(ks*128)*128 + tc*4;
        const float* sxp = sx + ks*128;
        float4 acc = make_float4(0.f,0.f,0.f,0.f);
        #pragma unroll 8
        for (int k = 0; k < 128; ++k) {
            float xk = sxp[k];
            float4 w = *(const float4*)(w1p + (size_t)k*128);
            acc.x = fmaf(xk, w.x, acc.x); acc.y = fmaf(xk, w.y, acc.y);
            acc.z = fmaf(xk, w.z, acc.z); acc.w = fmaf(xk, w.w, acc.w);
        }
        *(float4*)(&part1[ks][tc*4]) = acc;
    }
    __syncthreads();
    if (tid < 128) {
        float s = b1[tid];
        #pragma unroll
        for (int p = 0; p < 8; ++p) s += part1[p][tid];
        sh1[tid] = fmaxf(s, 0.0f);
    }
    __syncthreads();

    {   // layer 2: 128 -> 64, 4 k-slices of 32
        int ks2 = tid >> 6, to = tid & 63;
        float a = 0.f;
        #pragma unroll 8
        for (int k = 0; k < 32; ++k) {
            int kk = ks2*32 + k;
            a = fmaf(sh1[kk], w2[kk*64 + to], a);
        }
        part2[ks2][to] = a;
    }
    __syncthreads();
    if (tid < 64) {
        float s = b2[tid];
        #pragma unroll
        for (int p = 0; p < 4; ++p) s += part2[p][tid];
        sh2[tid] = fmaxf(s, 0.0f);
    }
    __syncthreads();

    if (tid < 64) {   // layer 3: 64 -> 8, 8 k-slices of 8
        int ks3 = tid >> 3, o = tid & 7;
        float a = 0.f;
        #pragma unroll
        for (int k = 0; k < 8; ++k) {
            int kk = ks3*8 + k;
            a = fmaf(sh2[kk], w3[kk*8 + o], a);
        }
        part3[ks3][o] = a;
    }
    __syncthreads();
    if (tid < 8) {
        float s = b3[tid];
        #pragma unroll
        for (int p = 0; p < 8; ++p) s += part3[p][tid];
        slog[tid] = s;
    }
    __syncthreads();
    if (tid == 0) {
        float m = slog[0];
        for (int i = 1; i < 8; ++i) m = fmaxf(m, slog[i]);
        float ssum = 0.0f;
        for (int i = 0; i < 8; ++i) ssum += expf(slog[i] - m);
        float lse = m + logf(ssum);
        for (int i = 0; i < 8; ++i) out[g*8 + i] = slog[i] - lse;
    }
}

extern "C" void kernel_launch(void* const* d_in, const int* in_sizes, int n_in,
                              void* d_out, int out_size, void* d_ws, size_t ws_size,
                              hipStream_t stream) {
    const float* x        = (const float*)d_in[0];
    const int*   ei       = (const int*)d_in[1];
    const float* W        = (const float*)d_in[4];
    const float* att_src  = (const float*)d_in[5];
    const float* att_dst  = (const float*)d_in[6];
    const float* bias     = (const float*)d_in[7];
    const float* topk_w   = (const float*)d_in[8];
    const float* w1       = (const float*)d_in[9];
    const float* b1       = (const float*)d_in[10];
    const float* w2       = (const float*)d_in[11];
    const float* b2       = (const float*)d_in[12];
    const float* w3       = (const float*)d_in[13];
    const float* b3       = (const float*)d_in[14];
    float* out = (float*)d_out;

    const int* src = ei;
    const int* dst = ei + E_EDGES;

    char* wsb = (char*)d_ws;
    size_t off = 0;
    auto alloc = [&](size_t bytes) -> void* {
        void* p = (void*)(wsb + off);
        off += (bytes + 255) & ~(size_t)255;
        return p;
    };
    float* h        = (float*)alloc((size_t)N_NODES*HD*4);
    float* x1       = (float*)alloc((size_t)N_NODES*HD*4);
    float* a_s      = (float*)alloc((size_t)N_NODES*4*4);
    float* a_d      = (float*)alloc((size_t)N_NODES*4*4);
    float* misc     = (float*)alloc(256);
    int*   counts   = (int*)alloc((size_t)N_NODES*4);
    int*   slots    = (int*)alloc((size_t)N_NODES*CAP*4);
    float* scores   = (float*)alloc((size_t)N_NODES*4);
    int*   kept_ids = (int*)alloc((size_t)B_GRAPHS*KKEEP*4);
    float* kept_vals= (float*)alloc((size_t)B_GRAPHS*KKEEP*4);
    float* pmax     = (float*)alloc((size_t)B_GRAPHS*NCHUNK*HD*4);
    float* psum     = (float*)alloc((size_t)B_GRAPHS*NCHUNK*HD*4);

    hipMemsetAsync(counts, 0, (size_t)N_NODES*4, stream);
    stage1_kernel<<<CH_BLOCKS + BS_BLOCKS + 1, 256, 0, stream>>>(
        x, W, att_src, att_dst, topk_w, dst, h, a_s, a_d, counts, slots, misc);
    gat_agg_kernel<<<N_NODES/8, 256, 0, stream>>>(h, a_s, a_d, counts, slots, src,
                                                  bias, topk_w, misc, x1, scores);
    topk_kernel<<<dim3(B_GRAPHS, 4), 256, 0, stream>>>(scores, kept_ids, kept_vals);
    pool_partial_kernel<<<B_GRAPHS*NCHUNK, 128, 0, stream>>>(x1, kept_ids, kept_vals, pmax, psum);
    mlp_kernel<<<B_GRAPHS, 256, 0, stream>>>(pmax, psum, w1, b1, w2, b2, w3, b3, out);
}

// Round 5
// 153.284 us; speedup vs baseline: 1.2269x; 1.2269x over previous
//
#include <hip/hip_runtime.h>
#include <math.h>

// Net_Without_GINEgPool: GATConv(32,128,h=4) + TopKPooling(0.8) + max/mean pool + MLP head.
// R5: back to R3 structure (separate prep/compute_h/build_slots; 1 node/wave, contiguous
//     column ownership). gat_agg trimmed: __expf, no-max softmax (exact), rcp, fast tanh,
//     CAP 32. Pool: 16 XCD-aligned chunks with 2-row unroll.

#define N_NODES 32000
#define B_GRAPHS 32
#define NPG 1000
#define DEGC 10
#define E_EDGES (N_NODES*DEGC)
#define HD 512
#define F_IN 32
#define KKEEP 800
#define SLOPE 0.2f
#define CAP 32

// ---------------- prep: Ws/Wd = W folded with att vectors; inv-norm of topk_w ----------------
__global__ void prep_kernel(const float* __restrict__ W, const float* __restrict__ att_src,
                            const float* __restrict__ att_dst, const float* __restrict__ topk_w,
                            float* __restrict__ Ws, float* __restrict__ Wd, float* __restrict__ misc)
{
    int tid = threadIdx.x; // 256
    if (tid < 128) {
        int f = tid >> 2, hh = tid & 3;
        float s1 = 0.f, s2 = 0.f;
        for (int d = 0; d < 128; ++d) {
            float w = W[f*HD + hh*128 + d];
            s1 = fmaf(w, att_src[hh*128 + d], s1);
            s2 = fmaf(w, att_dst[hh*128 + d], s2);
        }
        Ws[f*4+hh] = s1;
        Wd[f*4+hh] = s2;
    }
    __shared__ float red[256];
    float tw0 = topk_w[tid], tw1 = topk_w[tid+256];
    red[tid] = tw0*tw0 + tw1*tw1;
    __syncthreads();
    for (int s = 128; s > 0; s >>= 1) { if (tid < s) red[tid] += red[tid+s]; __syncthreads(); }
    if (tid == 0) misc[0] = 1.0f / sqrtf(red[0]);
}

// ---------------- h = x @ W  [N,512]; a_s = x @ Ws, a_d = x @ Wd  [N,4] ----------------
#define NPB 32
__global__ __launch_bounds__(256) void compute_h_kernel(
    const float* __restrict__ x, const float* __restrict__ W,
    const float* __restrict__ Ws, const float* __restrict__ Wd,
    float* __restrict__ h, float* __restrict__ a_s, float* __restrict__ a_d)
{
    __shared__ float s_x[NPB*F_IN];   // 4 KB
    int tid = threadIdx.x;            // 256
    int n0 = blockIdx.x * NPB;
    float wc0[F_IN], wc1[F_IN];
    #pragma unroll
    for (int f = 0; f < F_IN; ++f) {
        wc0[f] = W[f*HD + tid];
        wc1[f] = W[f*HD + tid + 256];
    }
    const float4* xg = (const float4*)(x + (size_t)n0*F_IN);
    float4* sx4 = (float4*)s_x;
    if (tid < NPB*F_IN/4) sx4[tid] = xg[tid];
    __syncthreads();
    for (int n = 0; n < NPB; ++n) {
        const float4* xr = (const float4*)(s_x + n*F_IN);
        float acc0 = 0.f, acc1 = 0.f;
        #pragma unroll
        for (int f4 = 0; f4 < F_IN/4; ++f4) {
            float4 xv = xr[f4];
            acc0 = fmaf(xv.x, wc0[f4*4+0], acc0); acc1 = fmaf(xv.x, wc1[f4*4+0], acc1);
            acc0 = fmaf(xv.y, wc0[f4*4+1], acc0); acc1 = fmaf(xv.y, wc1[f4*4+1], acc1);
            acc0 = fmaf(xv.z, wc0[f4*4+2], acc0); acc1 = fmaf(xv.z, wc1[f4*4+2], acc1);
            acc0 = fmaf(xv.w, wc0[f4*4+3], acc0); acc1 = fmaf(xv.w, wc1[f4*4+3], acc1);
        }
        h[(size_t)(n0+n)*HD + tid]       = acc0;
        h[(size_t)(n0+n)*HD + tid + 256] = acc1;
    }
    {
        int n = tid >> 3, hh = (tid >> 1) & 3, which = tid & 1;
        const float* Wx = which ? Wd : Ws;
        const float* xr = s_x + n*F_IN;
        float s = 0.f;
        #pragma unroll
        for (int f = 0; f < F_IN; ++f) s = fmaf(xr[f], Wx[f*4+hh], s);
        float* dp = which ? a_d : a_s;
        dp[(size_t)(n0+n)*4 + hh] = s;
    }
}

// ---------------- slot-table CSR: counts + fixed-capacity edge lists ----------------
__global__ void build_slots_kernel(const int* __restrict__ dst, int* __restrict__ counts,
                                   int* __restrict__ slots)
{
    int i = blockIdx.x*blockDim.x + threadIdx.x;
    int stride = gridDim.x*blockDim.x;
    for (; i < E_EDGES; i += stride) {
        int d = dst[i];
        int p = atomicAdd(&counts[d], 1);
        if (p < CAP) slots[d*CAP + p] = i;
    }
}

// ---------------- wave-per-node GAT: no-max softmax in registers + float4 aggregation ----------------
__global__ __launch_bounds__(256) void gat_agg_kernel(
    const float* __restrict__ h, const float* __restrict__ a_s, const float* __restrict__ a_d,
    const int* __restrict__ counts, const int* __restrict__ slots, const int* __restrict__ esrc,
    const float* __restrict__ bias, const float* __restrict__ topk_w, const float* __restrict__ misc,
    float* __restrict__ x1, float* __restrict__ scores)
{
    __shared__ int    s_src[4][CAP];
    __shared__ float4 s_al[4][CAP];
    int tid = threadIdx.x;
    int wid = tid >> 6, lane = tid & 63;
    // XCD swizzle: XCD k handles nodes [k*4000,(k+1)*4000)
    int grp  = (blockIdx.x & 7) * 1000 + (blockIdx.x >> 3);
    int node = grp*4 + wid;
    int deg  = min(counts[node], CAP);

    // deterministic edge order: rank-sort eids within the wave
    int key = (lane < deg) ? slots[node*CAP + lane] : (0x7FFF0000 + lane);
    int rank = 0;
    for (int j = 0; j < deg; ++j) rank += (__shfl(key, j, 64) < key);
    if (lane >= deg) rank = lane;
    int sorted_eid = __builtin_amdgcn_ds_permute(rank << 2, key);

    int src = node;
    if (lane < deg) src = esrc[sorted_eid];

    // attention logits (lane = edge, 4 heads in registers); softmax without max-shift
    // (exact: alpha = exp(e)/sum(exp(e)); |e| <~ 8 so no overflow)
    float4 ad    = *(const float4*)(a_d + (size_t)node*4);
    float4 aself = *(const float4*)(a_s + (size_t)node*4);
    float4 asrc  = make_float4(0.f,0.f,0.f,0.f);
    if (lane < deg) asrc = *(const float4*)(a_s + (size_t)src*4);

    float ex[4], exs[4];
    {
        float u;
        u = asrc.x + ad.x;  ex[0]  = u > 0.f ? u : SLOPE*u;
        u = asrc.y + ad.y;  ex[1]  = u > 0.f ? u : SLOPE*u;
        u = asrc.z + ad.z;  ex[2]  = u > 0.f ? u : SLOPE*u;
        u = asrc.w + ad.w;  ex[3]  = u > 0.f ? u : SLOPE*u;
        u = aself.x + ad.x; exs[0] = __expf(u > 0.f ? u : SLOPE*u);
        u = aself.y + ad.y; exs[1] = __expf(u > 0.f ? u : SLOPE*u);
        u = aself.z + ad.z; exs[2] = __expf(u > 0.f ? u : SLOPE*u);
        u = aself.w + ad.w; exs[3] = __expf(u > 0.f ? u : SLOPE*u);
    }
    float al[4], alself[4];
    #pragma unroll
    for (int hh = 0; hh < 4; ++hh) {
        float e = (lane < deg) ? __expf(ex[hh]) : 0.f;
        float den = e;
        #pragma unroll
        for (int msk = 1; msk < 64; msk <<= 1) den += __shfl_xor(den, msk, 64);
        den += exs[hh];
        float inv = __builtin_amdgcn_rcpf(den);
        al[hh]     = e * inv;
        alself[hh] = exs[hh] * inv;
    }
    if (lane < deg) {
        s_src[wid][lane] = src;
        s_al[wid][lane]  = make_float4(al[0], al[1], al[2], al[3]);
    }
    __syncthreads();

    // aggregation: lane owns cols [lane*4,+4) and [256+lane*4,+4)  (contiguous 1KB/instr)
    int c0 = lane*4, c1 = 256 + lane*4;
    bool hi = lane >= 32;                      // head of c0 = hi?1:0, head of c1 = hi?3:2
    float4 acc0 = make_float4(0.f,0.f,0.f,0.f);
    float4 acc1 = make_float4(0.f,0.f,0.f,0.f);
    #define EDGE_STEP(E_IDX)                                                          \
        {   int se = s_src[wid][E_IDX];                                               \
            float4 a4 = s_al[wid][E_IDX];                                             \
            float a0 = hi ? a4.y : a4.x;                                              \
            float a1 = hi ? a4.w : a4.z;                                              \
            float4 v0 = *(const float4*)(h + (size_t)se*HD + c0);                     \
            float4 v1 = *(const float4*)(h + (size_t)se*HD + c1);                     \
            acc0.x = fmaf(a0, v0.x, acc0.x); acc0.y = fmaf(a0, v0.y, acc0.y);         \
            acc0.z = fmaf(a0, v0.z, acc0.z); acc0.w = fmaf(a0, v0.w, acc0.w);         \
            acc1.x = fmaf(a1, v1.x, acc1.x); acc1.y = fmaf(a1, v1.y, acc1.y);         \
            acc1.z = fmaf(a1, v1.z, acc1.z); acc1.w = fmaf(a1, v1.w, acc1.w); }
    int e = 0;
    for (; e + 2 <= deg; e += 2) { EDGE_STEP(e); EDGE_STEP(e+1); }
    if (e < deg) EDGE_STEP(e);
    // self-loop last (reference concat order)
    {
        float a0 = hi ? alself[1] : alself[0];
        float a1 = hi ? alself[3] : alself[2];
        float4 v0 = *(const float4*)(h + (size_t)node*HD + c0);
        float4 v1 = *(const float4*)(h + (size_t)node*HD + c1);
        acc0.x = fmaf(a0, v0.x, acc0.x); acc0.y = fmaf(a0, v0.y, acc0.y);
        acc0.z = fmaf(a0, v0.z, acc0.z); acc0.w = fmaf(a0, v0.w, acc0.w);
        acc1.x = fmaf(a1, v1.x, acc1.x); acc1.y = fmaf(a1, v1.y, acc1.y);
        acc1.z = fmaf(a1, v1.z, acc1.z); acc1.w = fmaf(a1, v1.w, acc1.w);
    }
    #undef EDGE_STEP

    float4 b0 = *(const float4*)(bias + c0);
    float4 b1 = *(const float4*)(bias + c1);
    float4 v0, v1;
    v0.x = fmaxf(acc0.x + b0.x, 0.f); v0.y = fmaxf(acc0.y + b0.y, 0.f);
    v0.z = fmaxf(acc0.z + b0.z, 0.f); v0.w = fmaxf(acc0.w + b0.w, 0.f);
    v1.x = fmaxf(acc1.x + b1.x, 0.f); v1.y = fmaxf(acc1.y + b1.y, 0.f);
    v1.z = fmaxf(acc1.z + b1.z, 0.f); v1.w = fmaxf(acc1.w + b1.w, 0.f);
    *(float4*)(x1 + (size_t)node*HD + c0) = v0;
    *(float4*)(x1 + (size_t)node*HD + c1) = v1;

    float4 tw0 = *(const float4*)(topk_w + c0);
    float4 tw1 = *(const float4*)(topk_w + c1);
    float p = v0.x*tw0.x + v0.y*tw0.y + v0.z*tw0.z + v0.w*tw0.w
            + v1.x*tw1.x + v1.y*tw1.y + v1.z*tw1.z + v1.w*tw1.w;
    #pragma unroll
    for (int msk = 1; msk < 64; msk <<= 1) p += __shfl_xor(p, msk, 64);
    if (lane == 0) {
        float dotv = p * misc[0];
        float eu   = __expf(2.f * fabsf(dotv));       // tanh via exp, saturation-safe
        float th   = 1.f - 2.f/(eu + 1.f);
        scores[node] = copysignf(th, dotv);
    }
}

// ---------------- TopK per graph via exact rank; 4 blocks/graph ----------------
__global__ __launch_bounds__(256) void topk_kernel(const float* __restrict__ scores,
                                                   int* __restrict__ kept_ids,
                                                   float* __restrict__ kept_vals)
{
    int g = blockIdx.x, part = blockIdx.y;
    __shared__ float s[NPG];
    int tid = threadIdx.x;
    for (int i = tid; i < NPG; i += 256) s[i] = scores[g*NPG + i];
    __syncthreads();
    int i = part*250 + tid;
    if (tid < 250) {
        float si = s[i];
        int rank = 0;
        for (int j = 0; j < NPG; ++j) {
            float sj = s[j];
            rank += (sj > si) || (sj == si && j < i);
        }
        if (rank < KKEEP) {
            kept_ids[g*KKEEP + rank]  = g*NPG + i;
            kept_vals[g*KKEEP + rank] = si;
        }
    }
}

// ---------------- pool partials: 16 chunks x 50 rows, XCD-aligned, 2-row unroll ----------------
#define RCHUNK 50
#define NCHUNK 16
__global__ __launch_bounds__(128) void pool_partial_kernel(
    const float* __restrict__ x1, const int* __restrict__ kept_ids,
    const float* __restrict__ kept_vals, float* __restrict__ pmax, float* __restrict__ psum)
{
    int bid = blockIdx.x;                 // 512
    int k = bid & 7, q = bid >> 3;        // XCD k serves graphs 4k..4k+3
    int g = k*4 + (q & 3), c = q >> 2;    // c in [0,16)
    int tid = threadIdx.x;                // 128, float4 col = tid*4
    __shared__ int   ids[RCHUNK];
    __shared__ float vals[RCHUNK];
    if (tid < RCHUNK) {
        ids[tid]  = kept_ids[g*KKEEP + c*RCHUNK + tid];
        vals[tid] = kept_vals[g*KKEEP + c*RCHUNK + tid];
    }
    __syncthreads();
    float4 mxA = make_float4(-INFINITY,-INFINITY,-INFINITY,-INFINITY), mxB = mxA;
    float4 smA = make_float4(0.f,0.f,0.f,0.f), smB = smA;
    for (int r = 0; r < RCHUNK; r += 2) {
        float4 vA = *(const float4*)(x1 + (size_t)ids[r]*HD + tid*4);
        float4 vB = *(const float4*)(x1 + (size_t)ids[r+1]*HD + tid*4);
        float lA = vals[r], lB = vals[r+1];
        vA.x *= lA; vA.y *= lA; vA.z *= lA; vA.w *= lA;
        vB.x *= lB; vB.y *= lB; vB.z *= lB; vB.w *= lB;
        mxA.x = fmaxf(mxA.x, vA.x); mxA.y = fmaxf(mxA.y, vA.y);
        mxA.z = fmaxf(mxA.z, vA.z); mxA.w = fmaxf(mxA.w, vA.w);
        mxB.x = fmaxf(mxB.x, vB.x); mxB.y = fmaxf(mxB.y, vB.y);
        mxB.z = fmaxf(mxB.z, vB.z); mxB.w = fmaxf(mxB.w, vB.w);
        smA.x += vA.x; smA.y += vA.y; smA.z += vA.z; smA.w += vA.w;
        smB.x += vB.x; smB.y += vB.y; smB.z += vB.z; smB.w += vB.w;
    }
    float4 mx, sm;
    mx.x = fmaxf(mxA.x, mxB.x); mx.y = fmaxf(mxA.y, mxB.y);
    mx.z = fmaxf(mxA.z, mxB.z); mx.w = fmaxf(mxA.w, mxB.w);
    sm.x = smA.x + smB.x; sm.y = smA.y + smB.y;
    sm.z = smA.z + smB.z; sm.w = smA.w + smB.w;
    *(float4*)(pmax + (size_t)(g*NCHUNK + c)*HD + tid*4) = mx;
    *(float4*)(psum + (size_t)(g*NCHUNK + c)*HD + tid*4) = sm;
}

// ---------------- finalize pool + MLP head (k-split, 256 threads) ----------------
__global__ __launch_bounds__(256) void mlp_kernel(
    const float* __restrict__ pmax, const float* __restrict__ psum,
    const float* __restrict__ w1, const float* __restrict__ b1,
    const float* __restrict__ w2, const float* __restrict__ b2,
    const float* __restrict__ w3, const float* __restrict__ b3,
    float* __restrict__ out)
{
    int g = blockIdx.x;
    int tid = threadIdx.x; // 256
    __shared__ float sx[1024];
    __shared__ float part1[8][128];
    __shared__ float sh1[128];
    __shared__ float part2[4][64];
    __shared__ float sh2[64];
    __shared__ float part3[8][8];
    __shared__ float slog[8];

    {   // pool finalize over 16 partials
        int half = tid >> 7;           // 0 = max, 1 = mean
        int c4 = tid & 127;
        const float* basep = half ? psum : pmax;
        float4 r = *(const float4*)(basep + (size_t)(g*NCHUNK)*HD + c4*4);
        #pragma unroll
        for (int c = 1; c < NCHUNK; ++c) {
            float4 v = *(const float4*)(basep + (size_t)(g*NCHUNK + c)*HD + c4*4);
            if (half) { r.x += v.x; r.y += v.y; r.z += v.z; r.w += v.w; }
            else {
                r.x = fmaxf(r.x, v.x); r.y = fmaxf(r.y, v.y);
                r.z = fmaxf(r.z, v.z); r.w = fmaxf(r.w, v.w);
            }
        }
        if (half) { const float inv = 1.0f/KKEEP; r.x *= inv; r.y *= inv; r.z *= inv; r.w *= inv; }
        *(float4*)(sx + half*512 + c4*4) = r;
    }
    __syncthreads();

    {   // layer 1: 1024 -> 128, 8 k-slices of 128
        int ks = tid >> 5, tc = tid & 31;
        const float* w1p = w1 + (size_t)(ks*128)*128 + tc*4;
        const float* sxp = sx + ks*128;
        float4 acc = make_float4(0.f,0.f,0.f,0.f);
        #pragma unroll 8
        for (int k = 0; k < 128; ++k) {
            float xk = sxp[k];
            float4 w = *(const float4*)(w1p + (size_t)k*128);
            acc.x = fmaf(xk, w.x, acc.x); acc.y = fmaf(xk, w.y, acc.y);
            acc.z = fmaf(xk, w.z, acc.z); acc.w = fmaf(xk, w.w, acc.w);
        }
        *(float4*)(&part1[ks][tc*4]) = acc;
    }
    __syncthreads();
    if (tid < 128) {
        float s = b1[tid];
        #pragma unroll
        for (int p = 0; p < 8; ++p) s += part1[p][tid];
        sh1[tid] = fmaxf(s, 0.0f);
    }
    __syncthreads();

    {   // layer 2: 128 -> 64, 4 k-slices of 32
        int ks2 = tid >> 6, to = tid & 63;
        float a = 0.f;
        #pragma unroll 8
        for (int k = 0; k < 32; ++k) {
            int kk = ks2*32 + k;
            a = fmaf(sh1[kk], w2[kk*64 + to], a);
        }
        part2[ks2][to] = a;
    }
    __syncthreads();
    if (tid < 64) {
        float s = b2[tid];
        #pragma unroll
        for (int p = 0; p < 4; ++p) s += part2[p][tid];
        sh2[tid] = fmaxf(s, 0.0f);
    }
    __syncthreads();

    if (tid < 64) {   // layer 3: 64 -> 8, 8 k-slices of 8
        int ks3 = tid >> 3, o = tid & 7;
        float a = 0.f;
        #pragma unroll
        for (int k = 0; k < 8; ++k) {
            int kk = ks3*8 + k;
            a = fmaf(sh2[kk], w3[kk*8 + o], a);
        }
        part3[ks3][o] = a;
    }
    __syncthreads();
    if (tid < 8) {
        float s = b3[tid];
        #pragma unroll
        for (int p = 0; p < 8; ++p) s += part3[p][tid];
        slog[tid] = s;
    }
    __syncthreads();
    if (tid == 0) {
        float m = slog[0];
        for (int i = 1; i < 8; ++i) m = fmaxf(m, slog[i]);
        float ssum = 0.0f;
        for (int i = 0; i < 8; ++i) ssum += expf(slog[i] - m);
        float lse = m + logf(ssum);
        for (int i = 0; i < 8; ++i) out[g*8 + i] = slog[i] - lse;
    }
}

extern "C" void kernel_launch(void* const* d_in, const int* in_sizes, int n_in,
                              void* d_out, int out_size, void* d_ws, size_t ws_size,
                              hipStream_t stream) {
    const float* x        = (const float*)d_in[0];
    const int*   ei       = (const int*)d_in[1];
    const float* W        = (const float*)d_in[4];
    const float* att_src  = (const float*)d_in[5];
    const float* att_dst  = (const float*)d_in[6];
    const float* bias     = (const float*)d_in[7];
    const float* topk_w   = (const float*)d_in[8];
    const float* w1       = (const float*)d_in[9];
    const float* b1       = (const float*)d_in[10];
    const float* w2       = (const float*)d_in[11];
    const float* b2       = (const float*)d_in[12];
    const float* w3       = (const float*)d_in[13];
    const float* b3       = (const float*)d_in[14];
    float* out = (float*)d_out;

    const int* src = ei;
    const int* dst = ei + E_EDGES;

    char* wsb = (char*)d_ws;
    size_t off = 0;
    auto alloc = [&](size_t bytes) -> void* {
        void* p = (void*)(wsb + off);
        off += (bytes + 255) & ~(size_t)255;
        return p;
    };
    float* h        = (float*)alloc((size_t)N_NODES*HD*4);
    float* x1       = (float*)alloc((size_t)N_NODES*HD*4);
    float* a_s      = (float*)alloc((size_t)N_NODES*4*4);
    float* a_d      = (float*)alloc((size_t)N_NODES*4*4);
    float* Ws       = (float*)alloc(F_IN*4*4);
    float* Wd       = (float*)alloc(F_IN*4*4);
    float* misc     = (float*)alloc(256);
    int*   counts   = (int*)alloc((size_t)N_NODES*4);
    int*   slots    = (int*)alloc((size_t)N_NODES*CAP*4);
    float* scores   = (float*)alloc((size_t)N_NODES*4);
    int*   kept_ids = (int*)alloc((size_t)B_GRAPHS*KKEEP*4);
    float* kept_vals= (float*)alloc((size_t)B_GRAPHS*KKEEP*4);
    float* pmax     = (float*)alloc((size_t)B_GRAPHS*NCHUNK*HD*4);
    float* psum     = (float*)alloc((size_t)B_GRAPHS*NCHUNK*HD*4);

    hipMemsetAsync(counts, 0, (size_t)N_NODES*4, stream);
    prep_kernel<<<1, 256, 0, stream>>>(W, att_src, att_dst, topk_w, Ws, Wd, misc);
    compute_h_kernel<<<N_NODES/NPB, 256, 0, stream>>>(x, W, Ws, Wd, h, a_s, a_d);
    build_slots_kernel<<<640, 256, 0, stream>>>(dst, counts, slots);
    gat_agg_kernel<<<N_NODES/4, 256, 0, stream>>>(h, a_s, a_d, counts, slots, src,
                                                  bias, topk_w, misc, x1, scores);
    topk_kernel<<<dim3(B_GRAPHS, 4), 256, 0, stream>>>(scores, kept_ids, kept_vals);
    pool_partial_kernel<<<B_GRAPHS*NCHUNK, 128, 0, stream>>>(x1, kept_ids, kept_vals, pmax, psum);
    mlp_kernel<<<B_GRAPHS, 256, 0, stream>>>(pmax, psum, w1, b1, w2, b2, w3, b3, out);
}

// Round 6
// 145.852 us; speedup vs baseline: 1.2895x; 1.0510x over previous
//
#include <hip/hip_runtime.h>
#include <hip/hip_fp16.h>
#include <math.h>

// Net_Without_GINEgPool: GATConv(32,128,h=4) + TopKPooling(0.8) + max/mean pool + MLP head.
// R6: fp16 storage for h and x1 (the two 64MB streams). Per-XCD h slice now 4MB = L2-fit.
//     Scores still from fp32 accumulators (TopK ranking identical to R5). Rest = R5.

#define N_NODES 32000
#define B_GRAPHS 32
#define NPG 1000
#define DEGC 10
#define E_EDGES (N_NODES*DEGC)
#define HD 512
#define F_IN 32
#define KKEEP 800
#define SLOPE 0.2f
#define CAP 32

// ---------------- prep: Ws/Wd = W folded with att vectors; inv-norm of topk_w ----------------
__global__ void prep_kernel(const float* __restrict__ W, const float* __restrict__ att_src,
                            const float* __restrict__ att_dst, const float* __restrict__ topk_w,
                            float* __restrict__ Ws, float* __restrict__ Wd, float* __restrict__ misc)
{
    int tid = threadIdx.x; // 256
    if (tid < 128) {
        int f = tid >> 2, hh = tid & 3;
        float s1 = 0.f, s2 = 0.f;
        for (int d = 0; d < 128; ++d) {
            float w = W[f*HD + hh*128 + d];
            s1 = fmaf(w, att_src[hh*128 + d], s1);
            s2 = fmaf(w, att_dst[hh*128 + d], s2);
        }
        Ws[f*4+hh] = s1;
        Wd[f*4+hh] = s2;
    }
    __shared__ float red[256];
    float tw0 = topk_w[tid], tw1 = topk_w[tid+256];
    red[tid] = tw0*tw0 + tw1*tw1;
    __syncthreads();
    for (int s = 128; s > 0; s >>= 1) { if (tid < s) red[tid] += red[tid+s]; __syncthreads(); }
    if (tid == 0) misc[0] = 1.0f / sqrtf(red[0]);
}

// ---------------- h = x @ W  [N,512] fp16; a_s = x @ Ws, a_d = x @ Wd  [N,4] ----------------
#define NPB 32
__global__ __launch_bounds__(256) void compute_h_kernel(
    const float* __restrict__ x, const float* __restrict__ W,
    const float* __restrict__ Ws, const float* __restrict__ Wd,
    __half* __restrict__ h, float* __restrict__ a_s, float* __restrict__ a_d)
{
    __shared__ float s_x[NPB*F_IN];   // 4 KB
    int tid = threadIdx.x;            // 256; thread owns adjacent cols 2*tid, 2*tid+1
    int n0 = blockIdx.x * NPB;
    float wc0[F_IN], wc1[F_IN];
    #pragma unroll
    for (int f = 0; f < F_IN; ++f) {
        float2 wp = *(const float2*)(W + f*HD + 2*tid);
        wc0[f] = wp.x;
        wc1[f] = wp.y;
    }
    const float4* xg = (const float4*)(x + (size_t)n0*F_IN);
    float4* sx4 = (float4*)s_x;
    if (tid < NPB*F_IN/4) sx4[tid] = xg[tid];
    __syncthreads();
    for (int n = 0; n < NPB; ++n) {
        const float4* xr = (const float4*)(s_x + n*F_IN);
        float acc0 = 0.f, acc1 = 0.f;
        #pragma unroll
        for (int f4 = 0; f4 < F_IN/4; ++f4) {
            float4 xv = xr[f4];
            acc0 = fmaf(xv.x, wc0[f4*4+0], acc0); acc1 = fmaf(xv.x, wc1[f4*4+0], acc1);
            acc0 = fmaf(xv.y, wc0[f4*4+1], acc0); acc1 = fmaf(xv.y, wc1[f4*4+1], acc1);
            acc0 = fmaf(xv.z, wc0[f4*4+2], acc0); acc1 = fmaf(xv.z, wc1[f4*4+2], acc1);
            acc0 = fmaf(xv.w, wc0[f4*4+3], acc0); acc1 = fmaf(xv.w, wc1[f4*4+3], acc1);
        }
        *(__half2*)(h + (size_t)(n0+n)*HD + 2*tid) = __floats2half2_rn(acc0, acc1);
    }
    {
        int n = tid >> 3, hh = (tid >> 1) & 3, which = tid & 1;
        const float* Wx = which ? Wd : Ws;
        const float* xr = s_x + n*F_IN;
        float s = 0.f;
        #pragma unroll
        for (int f = 0; f < F_IN; ++f) s = fmaf(xr[f], Wx[f*4+hh], s);
        float* dp = which ? a_d : a_s;
        dp[(size_t)(n0+n)*4 + hh] = s;
    }
}

// ---------------- slot-table CSR: counts + fixed-capacity edge lists ----------------
__global__ void build_slots_kernel(const int* __restrict__ dst, int* __restrict__ counts,
                                   int* __restrict__ slots)
{
    int i = blockIdx.x*blockDim.x + threadIdx.x;
    int stride = gridDim.x*blockDim.x;
    for (; i < E_EDGES; i += stride) {
        int d = dst[i];
        int p = atomicAdd(&counts[d], 1);
        if (p < CAP) slots[d*CAP + p] = i;
    }
}

// ---------------- wave-per-node GAT: no-max softmax + fp16 gather/store ----------------
__global__ __launch_bounds__(256) void gat_agg_kernel(
    const __half* __restrict__ h, const float* __restrict__ a_s, const float* __restrict__ a_d,
    const int* __restrict__ counts, const int* __restrict__ slots, const int* __restrict__ esrc,
    const float* __restrict__ bias, const float* __restrict__ topk_w, const float* __restrict__ misc,
    __half* __restrict__ x1, float* __restrict__ scores)
{
    __shared__ int    s_src[4][CAP];
    __shared__ float4 s_al[4][CAP];
    int tid = threadIdx.x;
    int wid = tid >> 6, lane = tid & 63;
    // XCD swizzle: XCD k handles nodes [k*4000,(k+1)*4000)
    int grp  = (blockIdx.x & 7) * 1000 + (blockIdx.x >> 3);
    int node = grp*4 + wid;
    int deg  = min(counts[node], CAP);

    // deterministic edge order: rank-sort eids within the wave
    int key = (lane < deg) ? slots[node*CAP + lane] : (0x7FFF0000 + lane);
    int rank = 0;
    for (int j = 0; j < deg; ++j) rank += (__shfl(key, j, 64) < key);
    if (lane >= deg) rank = lane;
    int sorted_eid = __builtin_amdgcn_ds_permute(rank << 2, key);

    int src = node;
    if (lane < deg) src = esrc[sorted_eid];

    // attention logits; softmax without max-shift (exact; |logit| small)
    float4 ad    = *(const float4*)(a_d + (size_t)node*4);
    float4 aself = *(const float4*)(a_s + (size_t)node*4);
    float4 asrc  = make_float4(0.f,0.f,0.f,0.f);
    if (lane < deg) asrc = *(const float4*)(a_s + (size_t)src*4);

    float ex[4], exs[4];
    {
        float u;
        u = asrc.x + ad.x;  ex[0]  = u > 0.f ? u : SLOPE*u;
        u = asrc.y + ad.y;  ex[1]  = u > 0.f ? u : SLOPE*u;
        u = asrc.z + ad.z;  ex[2]  = u > 0.f ? u : SLOPE*u;
        u = asrc.w + ad.w;  ex[3]  = u > 0.f ? u : SLOPE*u;
        u = aself.x + ad.x; exs[0] = __expf(u > 0.f ? u : SLOPE*u);
        u = aself.y + ad.y; exs[1] = __expf(u > 0.f ? u : SLOPE*u);
        u = aself.z + ad.z; exs[2] = __expf(u > 0.f ? u : SLOPE*u);
        u = aself.w + ad.w; exs[3] = __expf(u > 0.f ? u : SLOPE*u);
    }
    float al[4], alself[4];
    #pragma unroll
    for (int hh = 0; hh < 4; ++hh) {
        float e = (lane < deg) ? __expf(ex[hh]) : 0.f;
        float den = e;
        #pragma unroll
        for (int msk = 1; msk < 64; msk <<= 1) den += __shfl_xor(den, msk, 64);
        den += exs[hh];
        float inv = __builtin_amdgcn_rcpf(den);
        al[hh]     = e * inv;
        alself[hh] = exs[hh] * inv;
    }
    if (lane < deg) {
        s_src[wid][lane] = src;
        s_al[wid][lane]  = make_float4(al[0], al[1], al[2], al[3]);
    }
    __syncthreads();

    // aggregation: lane owns cols [lane*4,+4) and [256+lane*4,+4); fp16 loads (8B/row-half)
    int c0 = lane*4, c1 = 256 + lane*4;
    bool hi = lane >= 32;                      // head of c0 = hi?1:0, head of c1 = hi?3:2
    float4 acc0 = make_float4(0.f,0.f,0.f,0.f);
    float4 acc1 = make_float4(0.f,0.f,0.f,0.f);
    #define EDGE_STEP(E_IDX)                                                          \
        {   int se = s_src[wid][E_IDX];                                               \
            float4 a4 = s_al[wid][E_IDX];                                             \
            float a0 = hi ? a4.y : a4.x;                                              \
            float a1 = hi ? a4.w : a4.z;                                              \
            const __half2* hp0 = (const __half2*)(h + (size_t)se*HD + c0);            \
            const __half2* hp1 = (const __half2*)(h + (size_t)se*HD + c1);            \
            __half2 q0 = hp0[0], q1 = hp0[1], q2 = hp1[0], q3 = hp1[1];               \
            float2 f0 = __half22float2(q0), f1 = __half22float2(q1);                  \
            float2 f2 = __half22float2(q2), f3 = __half22float2(q3);                  \
            acc0.x = fmaf(a0, f0.x, acc0.x); acc0.y = fmaf(a0, f0.y, acc0.y);         \
            acc0.z = fmaf(a0, f1.x, acc0.z); acc0.w = fmaf(a0, f1.y, acc0.w);         \
            acc1.x = fmaf(a1, f2.x, acc1.x); acc1.y = fmaf(a1, f2.y, acc1.y);         \
            acc1.z = fmaf(a1, f3.x, acc1.z); acc1.w = fmaf(a1, f3.y, acc1.w); }
    int e = 0;
    for (; e + 2 <= deg; e += 2) { EDGE_STEP(e); EDGE_STEP(e+1); }
    if (e < deg) EDGE_STEP(e);
    // self-loop last (reference concat order)
    {
        float a0 = hi ? alself[1] : alself[0];
        float a1 = hi ? alself[3] : alself[2];
        const __half2* hp0 = (const __half2*)(h + (size_t)node*HD + c0);
        const __half2* hp1 = (const __half2*)(h + (size_t)node*HD + c1);
        __half2 q0 = hp0[0], q1 = hp0[1], q2 = hp1[0], q3 = hp1[1];
        float2 f0 = __half22float2(q0), f1 = __half22float2(q1);
        float2 f2 = __half22float2(q2), f3 = __half22float2(q3);
        acc0.x = fmaf(a0, f0.x, acc0.x); acc0.y = fmaf(a0, f0.y, acc0.y);
        acc0.z = fmaf(a0, f1.x, acc0.z); acc0.w = fmaf(a0, f1.y, acc0.w);
        acc1.x = fmaf(a1, f2.x, acc1.x); acc1.y = fmaf(a1, f2.y, acc1.y);
        acc1.z = fmaf(a1, f3.x, acc1.z); acc1.w = fmaf(a1, f3.y, acc1.w);
    }
    #undef EDGE_STEP

    float4 b0 = *(const float4*)(bias + c0);
    float4 b1 = *(const float4*)(bias + c1);
    float4 v0, v1;
    v0.x = fmaxf(acc0.x + b0.x, 0.f); v0.y = fmaxf(acc0.y + b0.y, 0.f);
    v0.z = fmaxf(acc0.z + b0.z, 0.f); v0.w = fmaxf(acc0.w + b0.w, 0.f);
    v1.x = fmaxf(acc1.x + b1.x, 0.f); v1.y = fmaxf(acc1.y + b1.y, 0.f);
    v1.z = fmaxf(acc1.z + b1.z, 0.f); v1.w = fmaxf(acc1.w + b1.w, 0.f);
    {   // x1 store as fp16: pack 4 halves = 8B per segment, contiguous 512B/wave-instr
        __half2 p0 = __floats2half2_rn(v0.x, v0.y);
        __half2 p1 = __floats2half2_rn(v0.z, v0.w);
        __half2 p2 = __floats2half2_rn(v1.x, v1.y);
        __half2 p3 = __floats2half2_rn(v1.z, v1.w);
        __half2* xp0 = (__half2*)(x1 + (size_t)node*HD + c0);
        __half2* xp1 = (__half2*)(x1 + (size_t)node*HD + c1);
        xp0[0] = p0; xp0[1] = p1;
        xp1[0] = p2; xp1[1] = p3;
    }

    // topk score from fp32 accumulators (ranking unaffected by fp16 storage)
    float4 tw0 = *(const float4*)(topk_w + c0);
    float4 tw1 = *(const float4*)(topk_w + c1);
    float p = v0.x*tw0.x + v0.y*tw0.y + v0.z*tw0.z + v0.w*tw0.w
            + v1.x*tw1.x + v1.y*tw1.y + v1.z*tw1.z + v1.w*tw1.w;
    #pragma unroll
    for (int msk = 1; msk < 64; msk <<= 1) p += __shfl_xor(p, msk, 64);
    if (lane == 0) {
        float dotv = p * misc[0];
        float eu   = __expf(2.f * fabsf(dotv));       // tanh via exp, saturation-safe
        float th   = 1.f - 2.f/(eu + 1.f);
        scores[node] = copysignf(th, dotv);
    }
}

// ---------------- TopK per graph via exact rank; 4 blocks/graph ----------------
__global__ __launch_bounds__(256) void topk_kernel(const float* __restrict__ scores,
                                                   int* __restrict__ kept_ids,
                                                   float* __restrict__ kept_vals)
{
    int g = blockIdx.x, part = blockIdx.y;
    __shared__ float s[NPG];
    int tid = threadIdx.x;
    for (int i = tid; i < NPG; i += 256) s[i] = scores[g*NPG + i];
    __syncthreads();
    int i = part*250 + tid;
    if (tid < 250) {
        float si = s[i];
        int rank = 0;
        for (int j = 0; j < NPG; ++j) {
            float sj = s[j];
            rank += (sj > si) || (sj == si && j < i);
        }
        if (rank < KKEEP) {
            kept_ids[g*KKEEP + rank]  = g*NPG + i;
            kept_vals[g*KKEEP + rank] = si;
        }
    }
}

// ---------------- pool partials: 16 chunks x 50 rows, XCD-aligned, fp16 reads ----------------
#define RCHUNK 50
#define NCHUNK 16
__global__ __launch_bounds__(128) void pool_partial_kernel(
    const __half* __restrict__ x1, const int* __restrict__ kept_ids,
    const float* __restrict__ kept_vals, float* __restrict__ pmax, float* __restrict__ psum)
{
    int bid = blockIdx.x;                 // 512
    int k = bid & 7, q = bid >> 3;        // XCD k serves graphs 4k..4k+3
    int g = k*4 + (q & 3), c = q >> 2;    // c in [0,16)
    int tid = threadIdx.x;                // 128, 4-col group = tid*4
    __shared__ int   ids[RCHUNK];
    __shared__ float vals[RCHUNK];
    if (tid < RCHUNK) {
        ids[tid]  = kept_ids[g*KKEEP + c*RCHUNK + tid];
        vals[tid] = kept_vals[g*KKEEP + c*RCHUNK + tid];
    }
    __syncthreads();
    float4 mxA = make_float4(-INFINITY,-INFINITY,-INFINITY,-INFINITY), mxB = mxA;
    float4 smA = make_float4(0.f,0.f,0.f,0.f), smB = smA;
    for (int r = 0; r < RCHUNK; r += 2) {
        const __half2* pA = (const __half2*)(x1 + (size_t)ids[r]*HD + tid*4);
        const __half2* pB = (const __half2*)(x1 + (size_t)ids[r+1]*HD + tid*4);
        __half2 qA0 = pA[0], qA1 = pA[1], qB0 = pB[0], qB1 = pB[1];
        float2 a0 = __half22float2(qA0), a1 = __half22float2(qA1);
        float2 b0 = __half22float2(qB0), b1 = __half22float2(qB1);
        float lA = vals[r], lB = vals[r+1];
        float4 vA = make_float4(a0.x*lA, a0.y*lA, a1.x*lA, a1.y*lA);
        float4 vB = make_float4(b0.x*lB, b0.y*lB, b1.x*lB, b1.y*lB);
        mxA.x = fmaxf(mxA.x, vA.x); mxA.y = fmaxf(mxA.y, vA.y);
        mxA.z = fmaxf(mxA.z, vA.z); mxA.w = fmaxf(mxA.w, vA.w);
        mxB.x = fmaxf(mxB.x, vB.x); mxB.y = fmaxf(mxB.y, vB.y);
        mxB.z = fmaxf(mxB.z, vB.z); mxB.w = fmaxf(mxB.w, vB.w);
        smA.x += vA.x; smA.y += vA.y; smA.z += vA.z; smA.w += vA.w;
        smB.x += vB.x; smB.y += vB.y; smB.z += vB.z; smB.w += vB.w;
    }
    float4 mx, sm;
    mx.x = fmaxf(mxA.x, mxB.x); mx.y = fmaxf(mxA.y, mxB.y);
    mx.z = fmaxf(mxA.z, mxB.z); mx.w = fmaxf(mxA.w, mxB.w);
    sm.x = smA.x + smB.x; sm.y = smA.y + smB.y;
    sm.z = smA.z + smB.z; sm.w = smA.w + smB.w;
    *(float4*)(pmax + (size_t)(g*NCHUNK + c)*HD + tid*4) = mx;
    *(float4*)(psum + (size_t)(g*NCHUNK + c)*HD + tid*4) = sm;
}

// ---------------- finalize pool + MLP head (k-split, 256 threads) ----------------
__global__ __launch_bounds__(256) void mlp_kernel(
    const float* __restrict__ pmax, const float* __restrict__ psum,
    const float* __restrict__ w1, const float* __restrict__ b1,
    const float* __restrict__ w2, const float* __restrict__ b2,
    const float* __restrict__ w3, const float* __restrict__ b3,
    float* __restrict__ out)
{
    int g = blockIdx.x;
    int tid = threadIdx.x; // 256
    __shared__ float sx[1024];
    __shared__ float part1[8][128];
    __shared__ float sh1[128];
    __shared__ float part2[4][64];
    __shared__ float sh2[64];
    __shared__ float part3[8][8];
    __shared__ float slog[8];

    {   // pool finalize over 16 partials
        int half = tid >> 7;           // 0 = max, 1 = mean
        int c4 = tid & 127;
        const float* basep = half ? psum : pmax;
        float4 r = *(const float4*)(basep + (size_t)(g*NCHUNK)*HD + c4*4);
        #pragma unroll
        for (int c = 1; c < NCHUNK; ++c) {
            float4 v = *(const float4*)(basep + (size_t)(g*NCHUNK + c)*HD + c4*4);
            if (half) { r.x += v.x; r.y += v.y; r.z += v.z; r.w += v.w; }
            else {
                r.x = fmaxf(r.x, v.x); r.y = fmaxf(r.y, v.y);
                r.z = fmaxf(r.z, v.z); r.w = fmaxf(r.w, v.w);
            }
        }
        if (half) { const float inv = 1.0f/KKEEP; r.x *= inv; r.y *= inv; r.z *= inv; r.w *= inv; }
        *(float4*)(sx + half*512 + c4*4) = r;
    }
    __syncthreads();

    {   // layer 1: 1024 -> 128, 8 k-slices of 128
        int ks = tid >> 5, tc = tid & 31;
        const float* w1p = w1 + (size_t)(ks*128)*128 + tc*4;
        const float* sxp = sx + ks*128;
        float4 acc = make_float4(0.f,0.f,0.f,0.f);
        #pragma unroll 8
        for (int k = 0; k < 128; ++k) {
            float xk = sxp[k];
            float4 w = *(const float4*)(w1p + (size_t)k*128);
            acc.x = fmaf(xk, w.x, acc.x); acc.y = fmaf(xk, w.y, acc.y);
            acc.z = fmaf(xk, w.z, acc.z); acc.w = fmaf(xk, w.w, acc.w);
        }
        *(float4*)(&part1[ks][tc*4]) = acc;
    }
    __syncthreads();
    if (tid < 128) {
        float s = b1[tid];
        #pragma unroll
        for (int p = 0; p < 8; ++p) s += part1[p][tid];
        sh1[tid] = fmaxf(s, 0.0f);
    }
    __syncthreads();

    {   // layer 2: 128 -> 64, 4 k-slices of 32
        int ks2 = tid >> 6, to = tid & 63;
        float a = 0.f;
        #pragma unroll 8
        for (int k = 0; k < 32; ++k) {
            int kk = ks2*32 + k;
            a = fmaf(sh1[kk], w2[kk*64 + to], a);
        }
        part2[ks2][to] = a;
    }
    __syncthreads();
    if (tid < 64) {
        float s = b2[tid];
        #pragma unroll
        for (int p = 0; p < 4; ++p) s += part2[p][tid];
        sh2[tid] = fmaxf(s, 0.0f);
    }
    __syncthreads();

    if (tid < 64) {   // layer 3: 64 -> 8, 8 k-slices of 8
        int ks3 = tid >> 3, o = tid & 7;
        float a = 0.f;
        #pragma unroll
        for (int k = 0; k < 8; ++k) {
            int kk = ks3*8 + k;
            a = fmaf(sh2[kk], w3[kk*8 + o], a);
        }
        part3[ks3][o] = a;
    }
    __syncthreads();
    if (tid < 8) {
        float s = b3[tid];
        #pragma unroll
        for (int p = 0; p < 8; ++p) s += part3[p][tid];
        slog[tid] = s;
    }
    __syncthreads();
    if (tid == 0) {
        float m = slog[0];
        for (int i = 1; i < 8; ++i) m = fmaxf(m, slog[i]);
        float ssum = 0.0f;
        for (int i = 0; i < 8; ++i) ssum += expf(slog[i] - m);
        float lse = m + logf(ssum);
        for (int i = 0; i < 8; ++i) out[g*8 + i] = slog[i] - lse;
    }
}

extern "C" void kernel_launch(void* const* d_in, const int* in_sizes, int n_in,
                              void* d_out, int out_size, void* d_ws, size_t ws_size,
                              hipStream_t stream) {
    const float* x        = (const float*)d_in[0];
    const int*   ei       = (const int*)d_in[1];
    const float* W        = (const float*)d_in[4];
    const float* att_src  = (const float*)d_in[5];
    const float* att_dst  = (const float*)d_in[6];
    const float* bias     = (const float*)d_in[7];
    const float* topk_w   = (const float*)d_in[8];
    const float* w1       = (const float*)d_in[9];
    const float* b1       = (const float*)d_in[10];
    const float* w2       = (const float*)d_in[11];
    const float* b2       = (const float*)d_in[12];
    const float* w3       = (const float*)d_in[13];
    const float* b3       = (const float*)d_in[14];
    float* out = (float*)d_out;

    const int* src = ei;
    const int* dst = ei + E_EDGES;

    char* wsb = (char*)d_ws;
    size_t off = 0;
    auto alloc = [&](size_t bytes) -> void* {
        void* p = (void*)(wsb + off);
        off += (bytes + 255) & ~(size_t)255;
        return p;
    };
    __half* h       = (__half*)alloc((size_t)N_NODES*HD*2);
    __half* x1      = (__half*)alloc((size_t)N_NODES*HD*2);
    float* a_s      = (float*)alloc((size_t)N_NODES*4*4);
    float* a_d      = (float*)alloc((size_t)N_NODES*4*4);
    float* Ws       = (float*)alloc(F_IN*4*4);
    float* Wd       = (float*)alloc(F_IN*4*4);
    float* misc     = (float*)alloc(256);
    int*   counts   = (int*)alloc((size_t)N_NODES*4);
    int*   slots    = (int*)alloc((size_t)N_NODES*CAP*4);
    float* scores   = (float*)alloc((size_t)N_NODES*4);
    int*   kept_ids = (int*)alloc((size_t)B_GRAPHS*KKEEP*4);
    float* kept_vals= (float*)alloc((size_t)B_GRAPHS*KKEEP*4);
    float* pmax     = (float*)alloc((size_t)B_GRAPHS*NCHUNK*HD*4);
    float* psum     = (float*)alloc((size_t)B_GRAPHS*NCHUNK*HD*4);

    hipMemsetAsync(counts, 0, (size_t)N_NODES*4, stream);
    prep_kernel<<<1, 256, 0, stream>>>(W, att_src, att_dst, topk_w, Ws, Wd, misc);
    compute_h_kernel<<<N_NODES/NPB, 256, 0, stream>>>(x, W, Ws, Wd, h, a_s, a_d);
    build_slots_kernel<<<640, 256, 0, stream>>>(dst, counts, slots);
    gat_agg_kernel<<<N_NODES/4, 256, 0, stream>>>(h, a_s, a_d, counts, slots, src,
                                                  bias, topk_w, misc, x1, scores);
    topk_kernel<<<dim3(B_GRAPHS, 4), 256, 0, stream>>>(scores, kept_ids, kept_vals);
    pool_partial_kernel<<<B_GRAPHS*NCHUNK, 128, 0, stream>>>(x1, kept_ids, kept_vals, pmax, psum);
    mlp_kernel<<<B_GRAPHS, 256, 0, stream>>>(pmax, psum, w1, b1, w2, b2, w3, b3, out);
}

// Round 7
// 140.670 us; speedup vs baseline: 1.3370x; 1.0368x over previous
//
#include <hip/hip_runtime.h>
#include <hip/hip_fp16.h>
#include <math.h>

// Net_Without_GINEgPool: GATConv(32,128,h=4) + TopKPooling(0.8) + max/mean pool + MLP head.
// R7: (a) counts-zeroing fused into prep grid (removes 43us fillBufferAligned dispatch);
//     (b) gat_agg edge loop uses explicit v_fma_mix_f32 (fp16 src, fp32 accum) - no converts.
//     Numerics identical to R6 (absmax 0.0156 expected unchanged).

#define N_NODES 32000
#define B_GRAPHS 32
#define NPG 1000
#define DEGC 10
#define E_EDGES (N_NODES*DEGC)
#define HD 512
#define F_IN 32
#define KKEEP 800
#define SLOPE 0.2f
#define CAP 32

// ---------------- prep (block 0) + zero counts (blocks 1..32) ----------------
__global__ void prep_kernel(const float* __restrict__ W, const float* __restrict__ att_src,
                            const float* __restrict__ att_dst, const float* __restrict__ topk_w,
                            float* __restrict__ Ws, float* __restrict__ Wd, float* __restrict__ misc,
                            int* __restrict__ counts)
{
    int tid = threadIdx.x; // 256
    if (blockIdx.x > 0) {
        int i = (blockIdx.x - 1)*256 + tid;        // 8192 threads for 8000 int4s
        if (i < N_NODES/4) ((int4*)counts)[i] = make_int4(0,0,0,0);
        return;
    }
    if (tid < 128) {
        int f = tid >> 2, hh = tid & 3;
        float s1 = 0.f, s2 = 0.f;
        for (int d = 0; d < 128; ++d) {
            float w = W[f*HD + hh*128 + d];
            s1 = fmaf(w, att_src[hh*128 + d], s1);
            s2 = fmaf(w, att_dst[hh*128 + d], s2);
        }
        Ws[f*4+hh] = s1;
        Wd[f*4+hh] = s2;
    }
    __shared__ float red[256];
    float tw0 = topk_w[tid], tw1 = topk_w[tid+256];
    red[tid] = tw0*tw0 + tw1*tw1;
    __syncthreads();
    for (int s = 128; s > 0; s >>= 1) { if (tid < s) red[tid] += red[tid+s]; __syncthreads(); }
    if (tid == 0) misc[0] = 1.0f / sqrtf(red[0]);
}

// ---------------- h = x @ W  [N,512] fp16; a_s = x @ Ws, a_d = x @ Wd  [N,4] ----------------
#define NPB 32
__global__ __launch_bounds__(256) void compute_h_kernel(
    const float* __restrict__ x, const float* __restrict__ W,
    const float* __restrict__ Ws, const float* __restrict__ Wd,
    __half* __restrict__ h, float* __restrict__ a_s, float* __restrict__ a_d)
{
    __shared__ float s_x[NPB*F_IN];   // 4 KB
    int tid = threadIdx.x;            // 256; thread owns adjacent cols 2*tid, 2*tid+1
    int n0 = blockIdx.x * NPB;
    float wc0[F_IN], wc1[F_IN];
    #pragma unroll
    for (int f = 0; f < F_IN; ++f) {
        float2 wp = *(const float2*)(W + f*HD + 2*tid);
        wc0[f] = wp.x;
        wc1[f] = wp.y;
    }
    const float4* xg = (const float4*)(x + (size_t)n0*F_IN);
    float4* sx4 = (float4*)s_x;
    if (tid < NPB*F_IN/4) sx4[tid] = xg[tid];
    __syncthreads();
    for (int n = 0; n < NPB; ++n) {
        const float4* xr = (const float4*)(s_x + n*F_IN);
        float acc0 = 0.f, acc1 = 0.f;
        #pragma unroll
        for (int f4 = 0; f4 < F_IN/4; ++f4) {
            float4 xv = xr[f4];
            acc0 = fmaf(xv.x, wc0[f4*4+0], acc0); acc1 = fmaf(xv.x, wc1[f4*4+0], acc1);
            acc0 = fmaf(xv.y, wc0[f4*4+1], acc0); acc1 = fmaf(xv.y, wc1[f4*4+1], acc1);
            acc0 = fmaf(xv.z, wc0[f4*4+2], acc0); acc1 = fmaf(xv.z, wc1[f4*4+2], acc1);
            acc0 = fmaf(xv.w, wc0[f4*4+3], acc0); acc1 = fmaf(xv.w, wc1[f4*4+3], acc1);
        }
        *(__half2*)(h + (size_t)(n0+n)*HD + 2*tid) = __floats2half2_rn(acc0, acc1);
    }
    {
        int n = tid >> 3, hh = (tid >> 1) & 3, which = tid & 1;
        const float* Wx = which ? Wd : Ws;
        const float* xr = s_x + n*F_IN;
        float s = 0.f;
        #pragma unroll
        for (int f = 0; f < F_IN; ++f) s = fmaf(xr[f], Wx[f*4+hh], s);
        float* dp = which ? a_d : a_s;
        dp[(size_t)(n0+n)*4 + hh] = s;
    }
}

// ---------------- slot-table CSR: counts + fixed-capacity edge lists ----------------
__global__ void build_slots_kernel(const int* __restrict__ dst, int* __restrict__ counts,
                                   int* __restrict__ slots)
{
    int i = blockIdx.x*blockDim.x + threadIdx.x;
    int stride = gridDim.x*blockDim.x;
    for (; i < E_EDGES; i += stride) {
        int d = dst[i];
        int p = atomicAdd(&counts[d], 1);
        if (p < CAP) slots[d*CAP + p] = i;
    }
}

// ---------------- wave-per-node GAT: no-max softmax + fma_mix fp16 gather ----------------
__global__ __launch_bounds__(256) void gat_agg_kernel(
    const __half* __restrict__ h, const float* __restrict__ a_s, const float* __restrict__ a_d,
    const int* __restrict__ counts, const int* __restrict__ slots, const int* __restrict__ esrc,
    const float* __restrict__ bias, const float* __restrict__ topk_w, const float* __restrict__ misc,
    __half* __restrict__ x1, float* __restrict__ scores)
{
    __shared__ int    s_src[4][CAP];
    __shared__ float4 s_al[4][CAP];
    int tid = threadIdx.x;
    int wid = tid >> 6, lane = tid & 63;
    // XCD swizzle: XCD k handles nodes [k*4000,(k+1)*4000)
    int grp  = (blockIdx.x & 7) * 1000 + (blockIdx.x >> 3);
    int node = grp*4 + wid;
    int deg  = min(counts[node], CAP);

    // deterministic edge order: rank-sort eids within the wave
    int key = (lane < deg) ? slots[node*CAP + lane] : (0x7FFF0000 + lane);
    int rank = 0;
    for (int j = 0; j < deg; ++j) rank += (__shfl(key, j, 64) < key);
    if (lane >= deg) rank = lane;
    int sorted_eid = __builtin_amdgcn_ds_permute(rank << 2, key);

    int src = node;
    if (lane < deg) src = esrc[sorted_eid];

    // attention logits; softmax without max-shift (exact; |logit| small)
    float4 ad    = *(const float4*)(a_d + (size_t)node*4);
    float4 aself = *(const float4*)(a_s + (size_t)node*4);
    float4 asrc  = make_float4(0.f,0.f,0.f,0.f);
    if (lane < deg) asrc = *(const float4*)(a_s + (size_t)src*4);

    float ex[4], exs[4];
    {
        float u;
        u = asrc.x + ad.x;  ex[0]  = u > 0.f ? u : SLOPE*u;
        u = asrc.y + ad.y;  ex[1]  = u > 0.f ? u : SLOPE*u;
        u = asrc.z + ad.z;  ex[2]  = u > 0.f ? u : SLOPE*u;
        u = asrc.w + ad.w;  ex[3]  = u > 0.f ? u : SLOPE*u;
        u = aself.x + ad.x; exs[0] = __expf(u > 0.f ? u : SLOPE*u);
        u = aself.y + ad.y; exs[1] = __expf(u > 0.f ? u : SLOPE*u);
        u = aself.z + ad.z; exs[2] = __expf(u > 0.f ? u : SLOPE*u);
        u = aself.w + ad.w; exs[3] = __expf(u > 0.f ? u : SLOPE*u);
    }
    float al[4], alself[4];
    #pragma unroll
    for (int hh = 0; hh < 4; ++hh) {
        float e = (lane < deg) ? __expf(ex[hh]) : 0.f;
        float den = e;
        #pragma unroll
        for (int msk = 1; msk < 64; msk <<= 1) den += __shfl_xor(den, msk, 64);
        den += exs[hh];
        float inv = __builtin_amdgcn_rcpf(den);
        al[hh]     = e * inv;
        alself[hh] = exs[hh] * inv;
    }
    if (lane < deg) {
        s_src[wid][lane] = src;
        s_al[wid][lane]  = make_float4(al[0], al[1], al[2], al[3]);
    }
    __syncthreads();

    // aggregation: lane owns cols [lane*4,+4) and [256+lane*4,+4)
    // v_fma_mix_f32: fp16 source (op_sel_hi[1]=1), fp32 alpha + fp32 accumulator.
    int c0 = lane*4, c1 = 256 + lane*4;
    bool hi = lane >= 32;                      // head of c0 = hi?1:0, head of c1 = hi?3:2
    float f0=0.f,f1=0.f,f2=0.f,f3=0.f,f4=0.f,f5=0.f,f6=0.f,f7=0.f;
    #define MIX_LO(ACC,A,Q) asm("v_fma_mix_f32 %0, %1, %2, %0 op_sel_hi:[0,1,0]" : "+v"(ACC) : "v"(A), "v"(Q))
    #define MIX_HI(ACC,A,Q) asm("v_fma_mix_f32 %0, %1, %2, %0 op_sel:[0,1,0] op_sel_hi:[0,1,0]" : "+v"(ACC) : "v"(A), "v"(Q))
    #define EDGE_STEP(E_IDX)                                                          \
        {   int se = s_src[wid][E_IDX];                                               \
            float4 a4 = s_al[wid][E_IDX];                                             \
            float a0 = hi ? a4.y : a4.x;                                              \
            float a1 = hi ? a4.w : a4.z;                                              \
            uint2 q0 = *(const uint2*)(h + (size_t)se*HD + c0);                       \
            uint2 q1 = *(const uint2*)(h + (size_t)se*HD + c1);                       \
            MIX_LO(f0, a0, q0.x); MIX_HI(f1, a0, q0.x);                               \
            MIX_LO(f2, a0, q0.y); MIX_HI(f3, a0, q0.y);                               \
            MIX_LO(f4, a1, q1.x); MIX_HI(f5, a1, q1.x);                               \
            MIX_LO(f6, a1, q1.y); MIX_HI(f7, a1, q1.y); }
    int e = 0;
    for (; e + 2 <= deg; e += 2) { EDGE_STEP(e); EDGE_STEP(e+1); }
    if (e < deg) EDGE_STEP(e);
    // self-loop last (reference concat order)
    {
        float a0 = hi ? alself[1] : alself[0];
        float a1 = hi ? alself[3] : alself[2];
        uint2 q0 = *(const uint2*)(h + (size_t)node*HD + c0);
        uint2 q1 = *(const uint2*)(h + (size_t)node*HD + c1);
        MIX_LO(f0, a0, q0.x); MIX_HI(f1, a0, q0.x);
        MIX_LO(f2, a0, q0.y); MIX_HI(f3, a0, q0.y);
        MIX_LO(f4, a1, q1.x); MIX_HI(f5, a1, q1.x);
        MIX_LO(f6, a1, q1.y); MIX_HI(f7, a1, q1.y);
    }
    #undef EDGE_STEP
    #undef MIX_LO
    #undef MIX_HI

    float4 b0 = *(const float4*)(bias + c0);
    float4 b1 = *(const float4*)(bias + c1);
    float4 v0, v1;
    v0.x = fmaxf(f0 + b0.x, 0.f); v0.y = fmaxf(f1 + b0.y, 0.f);
    v0.z = fmaxf(f2 + b0.z, 0.f); v0.w = fmaxf(f3 + b0.w, 0.f);
    v1.x = fmaxf(f4 + b1.x, 0.f); v1.y = fmaxf(f5 + b1.y, 0.f);
    v1.z = fmaxf(f6 + b1.z, 0.f); v1.w = fmaxf(f7 + b1.w, 0.f);
    {   // x1 store as fp16
        __half2 p0 = __floats2half2_rn(v0.x, v0.y);
        __half2 p1 = __floats2half2_rn(v0.z, v0.w);
        __half2 p2 = __floats2half2_rn(v1.x, v1.y);
        __half2 p3 = __floats2half2_rn(v1.z, v1.w);
        __half2* xp0 = (__half2*)(x1 + (size_t)node*HD + c0);
        __half2* xp1 = (__half2*)(x1 + (size_t)node*HD + c1);
        xp0[0] = p0; xp0[1] = p1;
        xp1[0] = p2; xp1[1] = p3;
    }

    // topk score from fp32 accumulators
    float4 tw0 = *(const float4*)(topk_w + c0);
    float4 tw1 = *(const float4*)(topk_w + c1);
    float p = v0.x*tw0.x + v0.y*tw0.y + v0.z*tw0.z + v0.w*tw0.w
            + v1.x*tw1.x + v1.y*tw1.y + v1.z*tw1.z + v1.w*tw1.w;
    #pragma unroll
    for (int msk = 1; msk < 64; msk <<= 1) p += __shfl_xor(p, msk, 64);
    if (lane == 0) {
        float dotv = p * misc[0];
        float eu   = __expf(2.f * fabsf(dotv));       // tanh via exp, saturation-safe
        float th   = 1.f - 2.f/(eu + 1.f);
        scores[node] = copysignf(th, dotv);
    }
}

// ---------------- TopK per graph via exact rank; 4 blocks/graph ----------------
__global__ __launch_bounds__(256) void topk_kernel(const float* __restrict__ scores,
                                                   int* __restrict__ kept_ids,
                                                   float* __restrict__ kept_vals)
{
    int g = blockIdx.x, part = blockIdx.y;
    __shared__ float s[NPG];
    int tid = threadIdx.x;
    for (int i = tid; i < NPG; i += 256) s[i] = scores[g*NPG + i];
    __syncthreads();
    int i = part*250 + tid;
    if (tid < 250) {
        float si = s[i];
        int rank = 0;
        for (int j = 0; j < NPG; ++j) {
            float sj = s[j];
            rank += (sj > si) || (sj == si && j < i);
        }
        if (rank < KKEEP) {
            kept_ids[g*KKEEP + rank]  = g*NPG + i;
            kept_vals[g*KKEEP + rank] = si;
        }
    }
}

// ---------------- pool partials: 16 chunks x 50 rows, XCD-aligned, fp16 reads ----------------
#define RCHUNK 50
#define NCHUNK 16
__global__ __launch_bounds__(128) void pool_partial_kernel(
    const __half* __restrict__ x1, const int* __restrict__ kept_ids,
    const float* __restrict__ kept_vals, float* __restrict__ pmax, float* __restrict__ psum)
{
    int bid = blockIdx.x;                 // 512
    int k = bid & 7, q = bid >> 3;        // XCD k serves graphs 4k..4k+3
    int g = k*4 + (q & 3), c = q >> 2;    // c in [0,16)
    int tid = threadIdx.x;                // 128, 4-col group = tid*4
    __shared__ int   ids[RCHUNK];
    __shared__ float vals[RCHUNK];
    if (tid < RCHUNK) {
        ids[tid]  = kept_ids[g*KKEEP + c*RCHUNK + tid];
        vals[tid] = kept_vals[g*KKEEP + c*RCHUNK + tid];
    }
    __syncthreads();
    float4 mxA = make_float4(-INFINITY,-INFINITY,-INFINITY,-INFINITY), mxB = mxA;
    float4 smA = make_float4(0.f,0.f,0.f,0.f), smB = smA;
    for (int r = 0; r < RCHUNK; r += 2) {
        const __half2* pA = (const __half2*)(x1 + (size_t)ids[r]*HD + tid*4);
        const __half2* pB = (const __half2*)(x1 + (size_t)ids[r+1]*HD + tid*4);
        __half2 qA0 = pA[0], qA1 = pA[1], qB0 = pB[0], qB1 = pB[1];
        float2 a0 = __half22float2(qA0), a1 = __half22float2(qA1);
        float2 b0 = __half22float2(qB0), b1 = __half22float2(qB1);
        float lA = vals[r], lB = vals[r+1];
        float4 vA = make_float4(a0.x*lA, a0.y*lA, a1.x*lA, a1.y*lA);
        float4 vB = make_float4(b0.x*lB, b0.y*lB, b1.x*lB, b1.y*lB);
        mxA.x = fmaxf(mxA.x, vA.x); mxA.y = fmaxf(mxA.y, vA.y);
        mxA.z = fmaxf(mxA.z, vA.z); mxA.w = fmaxf(mxA.w, vA.w);
        mxB.x = fmaxf(mxB.x, vB.x); mxB.y = fmaxf(mxB.y, vB.y);
        mxB.z = fmaxf(mxB.z, vB.z); mxB.w = fmaxf(mxB.w, vB.w);
        smA.x += vA.x; smA.y += vA.y; smA.z += vA.z; smA.w += vA.w;
        smB.x += vB.x; smB.y += vB.y; smB.z += vB.z; smB.w += vB.w;
    }
    float4 mx, sm;
    mx.x = fmaxf(mxA.x, mxB.x); mx.y = fmaxf(mxA.y, mxB.y);
    mx.z = fmaxf(mxA.z, mxB.z); mx.w = fmaxf(mxA.w, mxB.w);
    sm.x = smA.x + smB.x; sm.y = smA.y + smB.y;
    sm.z = smA.z + smB.z; sm.w = smA.w + smB.w;
    *(float4*)(pmax + (size_t)(g*NCHUNK + c)*HD + tid*4) = mx;
    *(float4*)(psum + (size_t)(g*NCHUNK + c)*HD + tid*4) = sm;
}

// ---------------- finalize pool + MLP head (k-split, 256 threads) ----------------
__global__ __launch_bounds__(256) void mlp_kernel(
    const float* __restrict__ pmax, const float* __restrict__ psum,
    const float* __restrict__ w1, const float* __restrict__ b1,
    const float* __restrict__ w2, const float* __restrict__ b2,
    const float* __restrict__ w3, const float* __restrict__ b3,
    float* __restrict__ out)
{
    int g = blockIdx.x;
    int tid = threadIdx.x; // 256
    __shared__ float sx[1024];
    __shared__ float part1[8][128];
    __shared__ float sh1[128];
    __shared__ float part2[4][64];
    __shared__ float sh2[64];
    __shared__ float part3[8][8];
    __shared__ float slog[8];

    {   // pool finalize over 16 partials
        int half = tid >> 7;           // 0 = max, 1 = mean
        int c4 = tid & 127;
        const float* basep = half ? psum : pmax;
        float4 r = *(const float4*)(basep + (size_t)(g*NCHUNK)*HD + c4*4);
        #pragma unroll
        for (int c = 1; c < NCHUNK; ++c) {
            float4 v = *(const float4*)(basep + (size_t)(g*NCHUNK + c)*HD + c4*4);
            if (half) { r.x += v.x; r.y += v.y; r.z += v.z; r.w += v.w; }
            else {
                r.x = fmaxf(r.x, v.x); r.y = fmaxf(r.y, v.y);
                r.z = fmaxf(r.z, v.z); r.w = fmaxf(r.w, v.w);
            }
        }
        if (half) { const float inv = 1.0f/KKEEP; r.x *= inv; r.y *= inv; r.z *= inv; r.w *= inv; }
        *(float4*)(sx + half*512 + c4*4) = r;
    }
    __syncthreads();

    {   // layer 1: 1024 -> 128, 8 k-slices of 128
        int ks = tid >> 5, tc = tid & 31;
        const float* w1p = w1 + (size_t)(ks*128)*128 + tc*4;
        const float* sxp = sx + ks*128;
        float4 acc = make_float4(0.f,0.f,0.f,0.f);
        #pragma unroll 8
        for (int k = 0; k < 128; ++k) {
            float xk = sxp[k];
            float4 w = *(const float4*)(w1p + (size_t)k*128);
            acc.x = fmaf(xk, w.x, acc.x); acc.y = fmaf(xk, w.y, acc.y);
            acc.z = fmaf(xk, w.z, acc.z); acc.w = fmaf(xk, w.w, acc.w);
        }
        *(float4*)(&part1[ks][tc*4]) = acc;
    }
    __syncthreads();
    if (tid < 128) {
        float s = b1[tid];
        #pragma unroll
        for (int p = 0; p < 8; ++p) s += part1[p][tid];
        sh1[tid] = fmaxf(s, 0.0f);
    }
    __syncthreads();

    {   // layer 2: 128 -> 64, 4 k-slices of 32
        int ks2 = tid >> 6, to = tid & 63;
        float a = 0.f;
        #pragma unroll 8
        for (int k = 0; k < 32; ++k) {
            int kk = ks2*32 + k;
            a = fmaf(sh1[kk], w2[kk*64 + to], a);
        }
        part2[ks2][to] = a;
    }
    __syncthreads();
    if (tid < 64) {
        float s = b2[tid];
        #pragma unroll
        for (int p = 0; p < 4; ++p) s += part2[p][tid];
        sh2[tid] = fmaxf(s, 0.0f);
    }
    __syncthreads();

    if (tid < 64) {   // layer 3: 64 -> 8, 8 k-slices of 8
        int ks3 = tid >> 3, o = tid & 7;
        float a = 0.f;
        #pragma unroll
        for (int k = 0; k < 8; ++k) {
            int kk = ks3*8 + k;
            a = fmaf(sh2[kk], w3[kk*8 + o], a);
        }
        part3[ks3][o] = a;
    }
    __syncthreads();
    if (tid < 8) {
        float s = b3[tid];
        #pragma unroll
        for (int p = 0; p < 8; ++p) s += part3[p][tid];
        slog[tid] = s;
    }
    __syncthreads();
    if (tid == 0) {
        float m = slog[0];
        for (int i = 1; i < 8; ++i) m = fmaxf(m, slog[i]);
        float ssum = 0.0f;
        for (int i = 0; i < 8; ++i) ssum += expf(slog[i] - m);
        float lse = m + logf(ssum);
        for (int i = 0; i < 8; ++i) out[g*8 + i] = slog[i] - lse;
    }
}

extern "C" void kernel_launch(void* const* d_in, const int* in_sizes, int n_in,
                              void* d_out, int out_size, void* d_ws, size_t ws_size,
                              hipStream_t stream) {
    const float* x        = (const float*)d_in[0];
    const int*   ei       = (const int*)d_in[1];
    const float* W        = (const float*)d_in[4];
    const float* att_src  = (const float*)d_in[5];
    const float* att_dst  = (const float*)d_in[6];
    const float* bias     = (const float*)d_in[7];
    const float* topk_w   = (const float*)d_in[8];
    const float* w1       = (const float*)d_in[9];
    const float* b1       = (const float*)d_in[10];
    const float* w2       = (const float*)d_in[11];
    const float* b2       = (const float*)d_in[12];
    const float* w3       = (const float*)d_in[13];
    const float* b3       = (const float*)d_in[14];
    float* out = (float*)d_out;

    const int* src = ei;
    const int* dst = ei + E_EDGES;

    char* wsb = (char*)d_ws;
    size_t off = 0;
    auto alloc = [&](size_t bytes) -> void* {
        void* p = (void*)(wsb + off);
        off += (bytes + 255) & ~(size_t)255;
        return p;
    };
    __half* h       = (__half*)alloc((size_t)N_NODES*HD*2);
    __half* x1      = (__half*)alloc((size_t)N_NODES*HD*2);
    float* a_s      = (float*)alloc((size_t)N_NODES*4*4);
    float* a_d      = (float*)alloc((size_t)N_NODES*4*4);
    float* Ws       = (float*)alloc(F_IN*4*4);
    float* Wd       = (float*)alloc(F_IN*4*4);
    float* misc     = (float*)alloc(256);
    int*   counts   = (int*)alloc((size_t)N_NODES*4);
    int*   slots    = (int*)alloc((size_t)N_NODES*CAP*4);
    float* scores   = (float*)alloc((size_t)N_NODES*4);
    int*   kept_ids = (int*)alloc((size_t)B_GRAPHS*KKEEP*4);
    float* kept_vals= (float*)alloc((size_t)B_GRAPHS*KKEEP*4);
    float* pmax     = (float*)alloc((size_t)B_GRAPHS*NCHUNK*HD*4);
    float* psum     = (float*)alloc((size_t)B_GRAPHS*NCHUNK*HD*4);

    prep_kernel<<<33, 256, 0, stream>>>(W, att_src, att_dst, topk_w, Ws, Wd, misc, counts);
    compute_h_kernel<<<N_NODES/NPB, 256, 0, stream>>>(x, W, Ws, Wd, h, a_s, a_d);
    build_slots_kernel<<<640, 256, 0, stream>>>(dst, counts, slots);
    gat_agg_kernel<<<N_NODES/4, 256, 0, stream>>>(h, a_s, a_d, counts, slots, src,
                                                  bias, topk_w, misc, x1, scores);
    topk_kernel<<<dim3(B_GRAPHS, 4), 256, 0, stream>>>(scores, kept_ids, kept_vals);
    pool_partial_kernel<<<B_GRAPHS*NCHUNK, 128, 0, stream>>>(x1, kept_ids, kept_vals, pmax, psum);
    mlp_kernel<<<B_GRAPHS, 256, 0, stream>>>(pmax, psum, w1, b1, w2, b2, w3, b3, out);
}

// Round 8
// 119.149 us; speedup vs baseline: 1.5785x; 1.1806x over previous
//
#include <hip/hip_runtime.h>
#include <hip/hip_fp16.h>
#include <math.h>

// Net_Without_GINEgPool: GATConv(32,128,h=4) + TopKPooling(0.8) + max/mean pool + MLP head.
// R8: gat_agg 8-col-per-lane (1x uint4 load/edge, 1KB coalesced per instr); compute_h
//     XCD-aligned with gat's consumer swizzle + fused with build_slots (stage1).

#define N_NODES 32000
#define B_GRAPHS 32
#define NPG 1000
#define DEGC 10
#define E_EDGES (N_NODES*DEGC)
#define HD 512
#define F_IN 32
#define KKEEP 800
#define SLOPE 0.2f
#define CAP 32

// ---------------- prep (block 0) + zero counts (blocks 1..32) ----------------
__global__ void prep_kernel(const float* __restrict__ W, const float* __restrict__ att_src,
                            const float* __restrict__ att_dst, const float* __restrict__ topk_w,
                            float* __restrict__ Ws, float* __restrict__ Wd, float* __restrict__ misc,
                            int* __restrict__ counts)
{
    int tid = threadIdx.x; // 256
    if (blockIdx.x > 0) {
        int i = (blockIdx.x - 1)*256 + tid;
        if (i < N_NODES/4) ((int4*)counts)[i] = make_int4(0,0,0,0);
        return;
    }
    if (tid < 128) {
        int f = tid >> 2, hh = tid & 3;
        float s1 = 0.f, s2 = 0.f;
        for (int d = 0; d < 128; ++d) {
            float w = W[f*HD + hh*128 + d];
            s1 = fmaf(w, att_src[hh*128 + d], s1);
            s2 = fmaf(w, att_dst[hh*128 + d], s2);
        }
        Ws[f*4+hh] = s1;
        Wd[f*4+hh] = s2;
    }
    __shared__ float red[256];
    float tw0 = topk_w[tid], tw1 = topk_w[tid+256];
    red[tid] = tw0*tw0 + tw1*tw1;
    __syncthreads();
    for (int s = 128; s > 0; s >>= 1) { if (tid < s) red[tid] += red[tid+s]; __syncthreads(); }
    if (tid == 0) misc[0] = 1.0f / sqrtf(red[0]);
}

// ---------------- stage1: compute_h (XCD-aligned) | build_slots ----------------
#define NPB 32
#define CH_BLOCKS 1000
#define BS_BLOCKS 128
__global__ __launch_bounds__(256) void stage1_kernel(
    const float* __restrict__ x, const float* __restrict__ W,
    const float* __restrict__ Ws, const float* __restrict__ Wd,
    const int* __restrict__ dst,
    __half* __restrict__ h, float* __restrict__ a_s, float* __restrict__ a_d,
    int* __restrict__ counts, int* __restrict__ slots)
{
    int b = blockIdx.x;
    int tid = threadIdx.x;            // 256
    if (b < CH_BLOCKS) {
        // XCD-aligned: block b (on XCD b%8) computes nodes of gat's XCD-(b%8) range
        __shared__ float s_x[NPB*F_IN];   // 4 KB
        int n0 = (b & 7)*4000 + (b >> 3)*NPB;
        float wc0[F_IN], wc1[F_IN];
        #pragma unroll
        for (int f = 0; f < F_IN; ++f) {
            float2 wp = *(const float2*)(W + f*HD + 2*tid);
            wc0[f] = wp.x;
            wc1[f] = wp.y;
        }
        const float4* xg = (const float4*)(x + (size_t)n0*F_IN);
        float4* sx4 = (float4*)s_x;
        if (tid < NPB*F_IN/4) sx4[tid] = xg[tid];
        __syncthreads();
        for (int n = 0; n < NPB; ++n) {
            const float4* xr = (const float4*)(s_x + n*F_IN);
            float acc0 = 0.f, acc1 = 0.f;
            #pragma unroll
            for (int f4 = 0; f4 < F_IN/4; ++f4) {
                float4 xv = xr[f4];
                acc0 = fmaf(xv.x, wc0[f4*4+0], acc0); acc1 = fmaf(xv.x, wc1[f4*4+0], acc1);
                acc0 = fmaf(xv.y, wc0[f4*4+1], acc0); acc1 = fmaf(xv.y, wc1[f4*4+1], acc1);
                acc0 = fmaf(xv.z, wc0[f4*4+2], acc0); acc1 = fmaf(xv.z, wc1[f4*4+2], acc1);
                acc0 = fmaf(xv.w, wc0[f4*4+3], acc0); acc1 = fmaf(xv.w, wc1[f4*4+3], acc1);
            }
            *(__half2*)(h + (size_t)(n0+n)*HD + 2*tid) = __floats2half2_rn(acc0, acc1);
        }
        {
            int n = tid >> 3, hh = (tid >> 1) & 3, which = tid & 1;
            const float* Wx = which ? Wd : Ws;
            const float* xr = s_x + n*F_IN;
            float s = 0.f;
            #pragma unroll
            for (int f = 0; f < F_IN; ++f) s = fmaf(xr[f], Wx[f*4+hh], s);
            float* dp = which ? a_d : a_s;
            dp[(size_t)(n0+n)*4 + hh] = s;
        }
    } else {
        // build_slots: grid-stride over edges
        int i = (b - CH_BLOCKS)*256 + tid;
        int stride = BS_BLOCKS*256;
        for (; i < E_EDGES; i += stride) {
            int d = dst[i];
            int p = atomicAdd(&counts[d], 1);
            if (p < CAP) slots[d*CAP + p] = i;
        }
    }
}

// ---------------- wave-per-node GAT: 8 cols/lane, one uint4 gather per edge ----------------
__global__ __launch_bounds__(256) void gat_agg_kernel(
    const __half* __restrict__ h, const float* __restrict__ a_s, const float* __restrict__ a_d,
    const int* __restrict__ counts, const int* __restrict__ slots, const int* __restrict__ esrc,
    const float* __restrict__ bias, const float* __restrict__ topk_w, const float* __restrict__ misc,
    __half* __restrict__ x1, float* __restrict__ scores)
{
    __shared__ int    s_src[4][CAP];
    __shared__ float4 s_al4[4][CAP];
    int tid = threadIdx.x;
    int wid = tid >> 6, lane = tid & 63;
    // XCD swizzle: XCD k handles nodes [k*4000,(k+1)*4000)
    int grp  = (blockIdx.x & 7) * 1000 + (blockIdx.x >> 3);
    int node = grp*4 + wid;
    int deg  = min(counts[node], CAP);

    // deterministic edge order: rank-sort eids within the wave
    int key = (lane < deg) ? slots[node*CAP + lane] : (0x7FFF0000 + lane);
    int rank = 0;
    for (int j = 0; j < deg; ++j) rank += (__shfl(key, j, 64) < key);
    if (lane >= deg) rank = lane;
    int sorted_eid = __builtin_amdgcn_ds_permute(rank << 2, key);

    int src = node;
    if (lane < deg) src = esrc[sorted_eid];

    // attention logits; softmax without max-shift (exact; |logit| small)
    float4 ad    = *(const float4*)(a_d + (size_t)node*4);
    float4 aself = *(const float4*)(a_s + (size_t)node*4);
    float4 asrc  = make_float4(0.f,0.f,0.f,0.f);
    if (lane < deg) asrc = *(const float4*)(a_s + (size_t)src*4);

    float ex[4], exs[4];
    {
        float u;
        u = asrc.x + ad.x;  ex[0]  = u > 0.f ? u : SLOPE*u;
        u = asrc.y + ad.y;  ex[1]  = u > 0.f ? u : SLOPE*u;
        u = asrc.z + ad.z;  ex[2]  = u > 0.f ? u : SLOPE*u;
        u = asrc.w + ad.w;  ex[3]  = u > 0.f ? u : SLOPE*u;
        u = aself.x + ad.x; exs[0] = __expf(u > 0.f ? u : SLOPE*u);
        u = aself.y + ad.y; exs[1] = __expf(u > 0.f ? u : SLOPE*u);
        u = aself.z + ad.z; exs[2] = __expf(u > 0.f ? u : SLOPE*u);
        u = aself.w + ad.w; exs[3] = __expf(u > 0.f ? u : SLOPE*u);
    }
    float al[4], alself[4];
    #pragma unroll
    for (int hh = 0; hh < 4; ++hh) {
        float e = (lane < deg) ? __expf(ex[hh]) : 0.f;
        float den = e;
        #pragma unroll
        for (int msk = 1; msk < 64; msk <<= 1) den += __shfl_xor(den, msk, 64);
        den += exs[hh];
        float inv = __builtin_amdgcn_rcpf(den);
        al[hh]     = e * inv;
        alself[hh] = exs[hh] * inv;
    }
    if (lane < deg) {
        s_src[wid][lane] = src;
        s_al4[wid][lane] = make_float4(al[0], al[1], al[2], al[3]);
    }
    __syncthreads();

    // aggregation: lane owns 8 contiguous cols [lane*8, +8); head = lane>>4
    // one uint4 (16B) fp16 load per edge -> 1KB per wave-instruction, fully coalesced
    int head = lane >> 4;
    const __half* hb = h + lane*8;
    const float* alw = (const float*)&s_al4[wid][0];
    float f0=0.f,f1=0.f,f2=0.f,f3=0.f,f4=0.f,f5=0.f,f6=0.f,f7=0.f;
    #define MIX_LO(ACC,A,Q) asm("v_fma_mix_f32 %0, %1, %2, %0 op_sel_hi:[0,1,0]" : "+v"(ACC) : "v"(A), "v"(Q))
    #define MIX_HI(ACC,A,Q) asm("v_fma_mix_f32 %0, %1, %2, %0 op_sel:[0,1,0] op_sel_hi:[0,1,0]" : "+v"(ACC) : "v"(A), "v"(Q))
    #define EDGE_STEP(E_IDX)                                                          \
        {   int se = s_src[wid][E_IDX];                                               \
            float av = alw[(E_IDX)*4 + head];                                         \
            uint4 q = *(const uint4*)(hb + (size_t)se*HD);                            \
            MIX_LO(f0, av, q.x); MIX_HI(f1, av, q.x);                                 \
            MIX_LO(f2, av, q.y); MIX_HI(f3, av, q.y);                                 \
            MIX_LO(f4, av, q.z); MIX_HI(f5, av, q.z);                                 \
            MIX_LO(f6, av, q.w); MIX_HI(f7, av, q.w); }
    int e = 0;
    for (; e + 2 <= deg; e += 2) { EDGE_STEP(e); EDGE_STEP(e+1); }
    if (e < deg) EDGE_STEP(e);
    #undef EDGE_STEP
    // self-loop last (reference concat order); static-index alpha select
    {
        float a01 = (head & 1) ? alself[1] : alself[0];
        float a23 = (head & 1) ? alself[3] : alself[2];
        float av  = (head & 2) ? a23 : a01;
        uint4 q = *(const uint4*)(hb + (size_t)node*HD);
        MIX_LO(f0, av, q.x); MIX_HI(f1, av, q.x);
        MIX_LO(f2, av, q.y); MIX_HI(f3, av, q.y);
        MIX_LO(f4, av, q.z); MIX_HI(f5, av, q.z);
        MIX_LO(f6, av, q.w); MIX_HI(f7, av, q.w);
    }
    #undef MIX_LO
    #undef MIX_HI

    int c0 = lane*8;
    float4 b0 = *(const float4*)(bias + c0);
    float4 b1 = *(const float4*)(bias + c0 + 4);
    float v0 = fmaxf(f0 + b0.x, 0.f), v1 = fmaxf(f1 + b0.y, 0.f);
    float v2 = fmaxf(f2 + b0.z, 0.f), v3 = fmaxf(f3 + b0.w, 0.f);
    float v4 = fmaxf(f4 + b1.x, 0.f), v5 = fmaxf(f5 + b1.y, 0.f);
    float v6 = fmaxf(f6 + b1.z, 0.f), v7 = fmaxf(f7 + b1.w, 0.f);
    {   // single 16B fp16 store
        __half2 p0 = __floats2half2_rn(v0, v1);
        __half2 p1 = __floats2half2_rn(v2, v3);
        __half2 p2 = __floats2half2_rn(v4, v5);
        __half2 p3 = __floats2half2_rn(v6, v7);
        uint4 pk;
        pk.x = *(unsigned*)&p0; pk.y = *(unsigned*)&p1;
        pk.z = *(unsigned*)&p2; pk.w = *(unsigned*)&p3;
        *(uint4*)(x1 + (size_t)node*HD + c0) = pk;
    }

    // topk score from fp32 accumulators
    float4 tw0 = *(const float4*)(topk_w + c0);
    float4 tw1 = *(const float4*)(topk_w + c0 + 4);
    float p = v0*tw0.x + v1*tw0.y + v2*tw0.z + v3*tw0.w
            + v4*tw1.x + v5*tw1.y + v6*tw1.z + v7*tw1.w;
    #pragma unroll
    for (int msk = 1; msk < 64; msk <<= 1) p += __shfl_xor(p, msk, 64);
    if (lane == 0) {
        float dotv = p * misc[0];
        float eu   = __expf(2.f * fabsf(dotv));
        float th   = 1.f - 2.f/(eu + 1.f);
        scores[node] = copysignf(th, dotv);
    }
}

// ---------------- TopK per graph via exact rank; 4 blocks/graph ----------------
__global__ __launch_bounds__(256) void topk_kernel(const float* __restrict__ scores,
                                                   int* __restrict__ kept_ids,
                                                   float* __restrict__ kept_vals)
{
    int g = blockIdx.x, part = blockIdx.y;
    __shared__ float s[NPG];
    int tid = threadIdx.x;
    for (int i = tid; i < NPG; i += 256) s[i] = scores[g*NPG + i];
    __syncthreads();
    int i = part*250 + tid;
    if (tid < 250) {
        float si = s[i];
        int rank = 0;
        for (int j = 0; j < NPG; ++j) {
            float sj = s[j];
            rank += (sj > si) || (sj == si && j < i);
        }
        if (rank < KKEEP) {
            kept_ids[g*KKEEP + rank]  = g*NPG + i;
            kept_vals[g*KKEEP + rank] = si;
        }
    }
}

// ---------------- pool partials: 16 chunks x 50 rows, XCD-aligned, fp16 reads ----------------
#define RCHUNK 50
#define NCHUNK 16
__global__ __launch_bounds__(128) void pool_partial_kernel(
    const __half* __restrict__ x1, const int* __restrict__ kept_ids,
    const float* __restrict__ kept_vals, float* __restrict__ pmax, float* __restrict__ psum)
{
    int bid = blockIdx.x;                 // 512
    int k = bid & 7, q = bid >> 3;        // XCD k serves graphs 4k..4k+3
    int g = k*4 + (q & 3), c = q >> 2;    // c in [0,16)
    int tid = threadIdx.x;                // 128, 4-col group = tid*4
    __shared__ int   ids[RCHUNK];
    __shared__ float vals[RCHUNK];
    if (tid < RCHUNK) {
        ids[tid]  = kept_ids[g*KKEEP + c*RCHUNK + tid];
        vals[tid] = kept_vals[g*KKEEP + c*RCHUNK + tid];
    }
    __syncthreads();
    float4 mxA = make_float4(-INFINITY,-INFINITY,-INFINITY,-INFINITY), mxB = mxA;
    float4 smA = make_float4(0.f,0.f,0.f,0.f), smB = smA;
    for (int r = 0; r < RCHUNK; r += 2) {
        const __half2* pA = (const __half2*)(x1 + (size_t)ids[r]*HD + tid*4);
        const __half2* pB = (const __half2*)(x1 + (size_t)ids[r+1]*HD + tid*4);
        __half2 qA0 = pA[0], qA1 = pA[1], qB0 = pB[0], qB1 = pB[1];
        float2 a0 = __half22float2(qA0), a1 = __half22float2(qA1);
        float2 b0 = __half22float2(qB0), b1 = __half22float2(qB1);
        float lA = vals[r], lB = vals[r+1];
        float4 vA = make_float4(a0.x*lA, a0.y*lA, a1.x*lA, a1.y*lA);
        float4 vB = make_float4(b0.x*lB, b0.y*lB, b1.x*lB, b1.y*lB);
        mxA.x = fmaxf(mxA.x, vA.x); mxA.y = fmaxf(mxA.y, vA.y);
        mxA.z = fmaxf(mxA.z, vA.z); mxA.w = fmaxf(mxA.w, vA.w);
        mxB.x = fmaxf(mxB.x, vB.x); mxB.y = fmaxf(mxB.y, vB.y);
        mxB.z = fmaxf(mxB.z, vB.z); mxB.w = fmaxf(mxB.w, vB.w);
        smA.x += vA.x; smA.y += vA.y; smA.z += vA.z; smA.w += vA.w;
        smB.x += vB.x; smB.y += vB.y; smB.z += vB.z; smB.w += vB.w;
    }
    float4 mx, sm;
    mx.x = fmaxf(mxA.x, mxB.x); mx.y = fmaxf(mxA.y, mxB.y);
    mx.z = fmaxf(mxA.z, mxB.z); mx.w = fmaxf(mxA.w, mxB.w);
    sm.x = smA.x + smB.x; sm.y = smA.y + smB.y;
    sm.z = smA.z + smB.z; sm.w = smA.w + smB.w;
    *(float4*)(pmax + (size_t)(g*NCHUNK + c)*HD + tid*4) = mx;
    *(float4*)(psum + (size_t)(g*NCHUNK + c)*HD + tid*4) = sm;
}

// ---------------- finalize pool + MLP head (k-split, 256 threads) ----------------
__global__ __launch_bounds__(256) void mlp_kernel(
    const float* __restrict__ pmax, const float* __restrict__ psum,
    const float* __restrict__ w1, const float* __restrict__ b1,
    const float* __restrict__ w2, const float* __restrict__ b2,
    const float* __restrict__ w3, const float* __restrict__ b3,
    float* __restrict__ out)
{
    int g = blockIdx.x;
    int tid = threadIdx.x; // 256
    __shared__ float sx[1024];
    __shared__ float part1[8][128];
    __shared__ float sh1[128];
    __shared__ float part2[4][64];
    __shared__ float sh2[64];
    __shared__ float part3[8][8];
    __shared__ float slog[8];

    {   // pool finalize over 16 partials
        int half = tid >> 7;           // 0 = max, 1 = mean
        int c4 = tid & 127;
        const float* basep = half ? psum : pmax;
        float4 r = *(const float4*)(basep + (size_t)(g*NCHUNK)*HD + c4*4);
        #pragma unroll
        for (int c = 1; c < NCHUNK; ++c) {
            float4 v = *(const float4*)(basep + (size_t)(g*NCHUNK + c)*HD + c4*4);
            if (half) { r.x += v.x; r.y += v.y; r.z += v.z; r.w += v.w; }
            else {
                r.x = fmaxf(r.x, v.x); r.y = fmaxf(r.y, v.y);
                r.z = fmaxf(r.z, v.z); r.w = fmaxf(r.w, v.w);
            }
        }
        if (half) { const float inv = 1.0f/KKEEP; r.x *= inv; r.y *= inv; r.z *= inv; r.w *= inv; }
        *(float4*)(sx + half*512 + c4*4) = r;
    }
    __syncthreads();

    {   // layer 1: 1024 -> 128, 8 k-slices of 128
        int ks = tid >> 5, tc = tid & 31;
        const float* w1p = w1 + (size_t)(ks*128)*128 + tc*4;
        const float* sxp = sx + ks*128;
        float4 acc = make_float4(0.f,0.f,0.f,0.f);
        #pragma unroll 8
        for (int k = 0; k < 128; ++k) {
            float xk = sxp[k];
            float4 w = *(const float4*)(w1p + (size_t)k*128);
            acc.x = fmaf(xk, w.x, acc.x); acc.y = fmaf(xk, w.y, acc.y);
            acc.z = fmaf(xk, w.z, acc.z); acc.w = fmaf(xk, w.w, acc.w);
        }
        *(float4*)(&part1[ks][tc*4]) = acc;
    }
    __syncthreads();
    if (tid < 128) {
        float s = b1[tid];
        #pragma unroll
        for (int p = 0; p < 8; ++p) s += part1[p][tid];
        sh1[tid] = fmaxf(s, 0.0f);
    }
    __syncthreads();

    {   // layer 2: 128 -> 64, 4 k-slices of 32
        int ks2 = tid >> 6, to = tid & 63;
        float a = 0.f;
        #pragma unroll 8
        for (int k = 0; k < 32; ++k) {
            int kk = ks2*32 + k;
            a = fmaf(sh1[kk], w2[kk*64 + to], a);
        }
        part2[ks2][to] = a;
    }
    __syncthreads();
    if (tid < 64) {
        float s = b2[tid];
        #pragma unroll
        for (int p = 0; p < 4; ++p) s += part2[p][tid];
        sh2[tid] = fmaxf(s, 0.0f);
    }
    __syncthreads();

    if (tid < 64) {   // layer 3: 64 -> 8, 8 k-slices of 8
        int ks3 = tid >> 3, o = tid & 7;
        float a = 0.f;
        #pragma unroll
        for (int k = 0; k < 8; ++k) {
            int kk = ks3*8 + k;
            a = fmaf(sh2[kk], w3[kk*8 + o], a);
        }
        part3[ks3][o] = a;
    }
    __syncthreads();
    if (tid < 8) {
        float s = b3[tid];
        #pragma unroll
        for (int p = 0; p < 8; ++p) s += part3[p][tid];
        slog[tid] = s;
    }
    __syncthreads();
    if (tid == 0) {
        float m = slog[0];
        for (int i = 1; i < 8; ++i) m = fmaxf(m, slog[i]);
        float ssum = 0.0f;
        for (int i = 0; i < 8; ++i) ssum += expf(slog[i] - m);
        float lse = m + logf(ssum);
        for (int i = 0; i < 8; ++i) out[g*8 + i] = slog[i] - lse;
    }
}

extern "C" void kernel_launch(void* const* d_in, const int* in_sizes, int n_in,
                              void* d_out, int out_size, void* d_ws, size_t ws_size,
                              hipStream_t stream) {
    const float* x        = (const float*)d_in[0];
    const int*   ei       = (const int*)d_in[1];
    const float* W        = (const float*)d_in[4];
    const float* att_src  = (const float*)d_in[5];
    const float* att_dst  = (const float*)d_in[6];
    const float* bias     = (const float*)d_in[7];
    const float* topk_w   = (const float*)d_in[8];
    const float* w1       = (const float*)d_in[9];
    const float* b1       = (const float*)d_in[10];
    const float* w2       = (const float*)d_in[11];
    const float* b2       = (const float*)d_in[12];
    const float* w3       = (const float*)d_in[13];
    const float* b3       = (const float*)d_in[14];
    float* out = (float*)d_out;

    const int* src = ei;
    const int* dst = ei + E_EDGES;

    char* wsb = (char*)d_ws;
    size_t off = 0;
    auto alloc = [&](size_t bytes) -> void* {
        void* p = (void*)(wsb + off);
        off += (bytes + 255) & ~(size_t)255;
        return p;
    };
    __half* h       = (__half*)alloc((size_t)N_NODES*HD*2);
    __half* x1      = (__half*)alloc((size_t)N_NODES*HD*2);
    float* a_s      = (float*)alloc((size_t)N_NODES*4*4);
    float* a_d      = (float*)alloc((size_t)N_NODES*4*4);
    float* Ws       = (float*)alloc(F_IN*4*4);
    float* Wd       = (float*)alloc(F_IN*4*4);
    float* misc     = (float*)alloc(256);
    int*   counts   = (int*)alloc((size_t)N_NODES*4);
    int*   slots    = (int*)alloc((size_t)N_NODES*CAP*4);
    float* scores   = (float*)alloc((size_t)N_NODES*4);
    int*   kept_ids = (int*)alloc((size_t)B_GRAPHS*KKEEP*4);
    float* kept_vals= (float*)alloc((size_t)B_GRAPHS*KKEEP*4);
    float* pmax     = (float*)alloc((size_t)B_GRAPHS*NCHUNK*HD*4);
    float* psum     = (float*)alloc((size_t)B_GRAPHS*NCHUNK*HD*4);

    prep_kernel<<<33, 256, 0, stream>>>(W, att_src, att_dst, topk_w, Ws, Wd, misc, counts);
    stage1_kernel<<<CH_BLOCKS + BS_BLOCKS, 256, 0, stream>>>(
        x, W, Ws, Wd, dst, h, a_s, a_d, counts, slots);
    gat_agg_kernel<<<N_NODES/4, 256, 0, stream>>>(h, a_s, a_d, counts, slots, src,
                                                  bias, topk_w, misc, x1, scores);
    topk_kernel<<<dim3(B_GRAPHS, 4), 256, 0, stream>>>(scores, kept_ids, kept_vals);
    pool_partial_kernel<<<B_GRAPHS*NCHUNK, 128, 0, stream>>>(x1, kept_ids, kept_vals, pmax, psum);
    mlp_kernel<<<B_GRAPHS, 256, 0, stream>>>(pmax, psum, w1, b1, w2, b2, w3, b3, out);
}